// Round 2
// baseline (11870.798 us; speedup 1.0000x reference)
//
#include <hip/hip_runtime.h>
#include <hip/hip_bf16.h>
#include <math.h>

#define N_NODES 50000
#define N_EDGES 1600000

// ---------------- workspace layout (bytes) ----------------
static const size_t H_OFF    = 0;                        // h   [N][512] f32
static const size_t AGG_OFF  = 102400000;                // agg [N][512] f32
static const size_t EI_OFF   = 204800000;                // int32 [2][E] canonical edge index
static const size_t DEG_OFF  = 217600000;                // int [N]
static const size_t DIS_OFF  = 217800192;                // f32 [N] deg_inv_sqrt
static const size_t DINV_OFF = 218000384;                // f32 [N] 1/deg
static const size_t WT_OFF   = 218200576;                // Wt [256][768] f32 (in_proj_w^T)
static const size_t WP_OFF   = 218987008;                // w' [256]
static const size_t U_OFF    = 218988032;                // u  [8][256]
static const size_t CH_OFF   = 218996224;                // c  [8]
static const size_t FLAG_OFF = 218996480;                // int flag: 1 = int32 layout
static const size_t ACC_OFF  = 218996736;                // double accumulator
static const size_t WS_NEED  = 218996992;

// ---------------- kernels ----------------

__global__ void k_guard(float* out) { if (threadIdx.x == 0) out[0] = -12345.0f; }

// probe raw edge buffer: int64 layout has all odd int32 words == 0 (ids < 2^31)
__global__ void k_detect(const int* __restrict__ raw, int* __restrict__ flag) {
    if (raw[2 * threadIdx.x + 1] != 0) atomicOr(flag, 1);
}

// normalize to canonical int32 [2][E]
__global__ __launch_bounds__(256) void k_cvt(const int* __restrict__ raw,
                                             const int* __restrict__ flag,
                                             int* __restrict__ out) {
    int e = blockIdx.x * 256 + threadIdx.x;
    if (e >= N_EDGES) return;
    if (*flag) {                      // already int32
        out[e]            = raw[e];
        out[N_EDGES + e]  = raw[N_EDGES + e];
    } else {                          // int64: take low words
        out[e]            = raw[2 * e];
        out[N_EDGES + e]  = raw[2 * (size_t)N_EDGES + 2 * e];
    }
}

__global__ __launch_bounds__(256) void k_deg(const int* __restrict__ ei, int* __restrict__ cnt) {
    int e = blockIdx.x * 256 + threadIdx.x;
    if (e < N_EDGES) atomicAdd(&cnt[ei[N_EDGES + e]], 1);
}

__global__ __launch_bounds__(256) void k_norm(const int* __restrict__ cnt,
                                              float* __restrict__ dis, float* __restrict__ dinv) {
    int n = blockIdx.x * 256 + threadIdx.x;
    if (n < N_NODES) {
        float d = 1.0f + (float)cnt[n];
        float r = rsqrtf(d);
        dis[n]  = r;
        dinv[n] = r * r;
    }
}

// h[n, 0:256] = x[n,0:100] @ W_s ; h[n,256:512] = x[n,100:300] @ W_f   (no bias here)
__global__ __launch_bounds__(256) void k_hgemm(const float* __restrict__ x,
                                               const float* __restrict__ Ws,
                                               const float* __restrict__ Wf,
                                               float* __restrict__ h) {
    __shared__ float xs[32][201];
    int tid  = threadIdx.x;
    int n0   = blockIdx.x * 32;
    int half = blockIdx.y >> 2;          // 0: s-features, 1: f-features
    int cg   = blockIdx.y & 3;           // column group of 64
    int K    = half ? 200 : 100;
    int xoff = half ? 100 : 0;
    const float* W = half ? Wf : Ws;
    int base = half ? 256 : 0;

    for (int idx = tid; idx < 32 * K; idx += 256) {
        int nd = idx / K, kk = idx - nd * K;
        int n = n0 + nd;
        xs[nd][kk] = (n < N_NODES) ? x[(size_t)n * 300 + xoff + kk] : 0.0f;
    }
    __syncthreads();

    int cgrp = tid & 15, rgrp = tid >> 4;
    int c0 = cg * 64 + cgrp * 4;
    int r0 = rgrp * 2, r1 = r0 + 1;
    float a00=0,a01=0,a02=0,a03=0, a10=0,a11=0,a12=0,a13=0;
    for (int k = 0; k < K; ++k) {
        float4 b = *reinterpret_cast<const float4*>(&W[k * 256 + c0]);
        float p0 = xs[r0][k], p1 = xs[r1][k];
        a00 += p0*b.x; a01 += p0*b.y; a02 += p0*b.z; a03 += p0*b.w;
        a10 += p1*b.x; a11 += p1*b.y; a12 += p1*b.z; a13 += p1*b.w;
    }
    int n_a = n0 + r0, n_b = n0 + r1;
    if (n_a < N_NODES) {
        float4 v = make_float4(a00,a01,a02,a03);
        *reinterpret_cast<float4*>(&h[(size_t)n_a * 512 + base + c0]) = v;
    }
    if (n_b < N_NODES) {
        float4 v = make_float4(a10,a11,a12,a13);
        *reinterpret_cast<float4*>(&h[(size_t)n_b * 512 + base + c0]) = v;
    }
}

// one wave per edge: agg[dst] += coef * h[src]   (512 channels)
__global__ __launch_bounds__(256) void k_edge(const int* __restrict__ ei,
                                              const float* __restrict__ dis,
                                              const float* __restrict__ h,
                                              float* __restrict__ agg) {
    int lane = threadIdx.x & 63;
    int e = blockIdx.x * 4 + (threadIdx.x >> 6);
    if (e >= N_EDGES) return;
    int s = ei[e], d = ei[N_EDGES + e];
    float c = dis[s] * dis[d];
    const float4* hs = reinterpret_cast<const float4*>(h + (size_t)s * 512);
    float* ad = agg + (size_t)d * 512;
    float4 v0 = hs[lane];
    float4 v1 = hs[lane + 64];
    atomicAdd(&ad[4*lane + 0],  c*v0.x); atomicAdd(&ad[4*lane + 1],  c*v0.y);
    atomicAdd(&ad[4*lane + 2],  c*v0.z); atomicAdd(&ad[4*lane + 3],  c*v0.w);
    atomicAdd(&ad[4*(lane+64)+0], c*v1.x); atomicAdd(&ad[4*(lane+64)+1], c*v1.y);
    atomicAdd(&ad[4*(lane+64)+2], c*v1.z); atomicAdd(&ad[4*(lane+64)+3], c*v1.w);
}

// Wt[k][j] = in_proj_w[j][k]
__global__ __launch_bounds__(256) void k_tr(const float* __restrict__ ipw, float* __restrict__ Wt) {
    int k = blockIdx.x;
    for (int j = threadIdx.x; j < 768; j += 256)
        Wt[k * 768 + j] = ipw[(size_t)j * 256 + k];
}

// w'[i] = sum_j out_w[j] * out_proj_w[j][i]
__global__ __launch_bounds__(256) void k_wprime(const float* __restrict__ ow,
                                                const float* __restrict__ opw,
                                                float* __restrict__ wp) {
    int i = threadIdx.x;
    float s = 0.0f;
    for (int j = 0; j < 256; ++j) s += ow[j] * opw[j * 256 + i];
    wp[i] = s;
}

// u[h][i] = sum_d ipw[512+h*32+d][i] * w'[h*32+d] ;  c[h] = sum_d ipb[512+h*32+d]*w'[h*32+d]
__global__ __launch_bounds__(256) void k_u(const float* __restrict__ ipw,
                                           const float* __restrict__ ipb,
                                           const float* __restrict__ wp,
                                           float* __restrict__ u, float* __restrict__ ch) {
    int hd = blockIdx.x, i = threadIdx.x;
    float s = 0.0f;
    for (int d = 0; d < 32; ++d)
        s += ipw[(size_t)(512 + hd * 32 + d) * 256 + i] * wp[hd * 32 + d];
    u[hd * 256 + i] = s;
    if (i == 0) {
        float c = 0.0f;
        for (int d = 0; d < 32; ++d) c += ipb[512 + hd * 32 + d] * wp[hd * 32 + d];
        ch[hd] = c;
    }
}

// fused: comb = relu(agg + dinv*h + b) -> per-head q/k GEMM -> softmax -> vw combine -> reduce
__global__ __launch_bounds__(256) void k_attn(const float* __restrict__ h,
                                              const float* __restrict__ agg,
                                              const float* __restrict__ dinv,
                                              const float* __restrict__ bs,
                                              const float* __restrict__ bf,
                                              const float* __restrict__ Wt,
                                              const float* __restrict__ ipb,
                                              const float* __restrict__ u,
                                              const float* __restrict__ ch,
                                              double* __restrict__ accum) {
    __shared__ float comb[32][257];   // 16 nodes x 2 tokens, padded
    __shared__ float qk[32][65];      // cols 0..31 q, 32..63 k, padded
    __shared__ float vw[32];
    __shared__ float red[16];

    int tid = threadIdx.x;
    int n0  = blockIdx.x * 16;

    // stage comb tile
    for (int idx = tid; idx < 32 * 256; idx += 256) {
        int row = idx >> 8, j = idx & 255;
        int n = n0 + (row >> 1), t = row & 1;
        float v = 0.0f;
        if (n < N_NODES) {
            size_t o = (size_t)n * 512 + t * 256 + j;
            v = agg[o] + dinv[n] * h[o] + (t ? bf[j] : bs[j]);
            v = fmaxf(v, 0.0f);
        }
        comb[row][j] = v;
    }
    __syncthreads();

    int cgrp = tid & 15, rgrp = tid >> 4;
    int c0 = cgrp * 4;
    int r0 = rgrp * 2, r1 = r0 + 1;
    float nodeAcc = 0.0f;

    for (int hd = 0; hd < 8; ++hd) {
        int j0 = (c0 < 32) ? (hd * 32 + c0) : (256 + hd * 32 + (c0 - 32));
        float a00=0,a01=0,a02=0,a03=0, a10=0,a11=0,a12=0,a13=0;
        for (int k = 0; k < 256; ++k) {
            float4 b = *reinterpret_cast<const float4*>(&Wt[k * 768 + j0]);
            float p0 = comb[r0][k], p1 = comb[r1][k];
            a00 += p0*b.x; a01 += p0*b.y; a02 += p0*b.z; a03 += p0*b.w;
            a10 += p1*b.x; a11 += p1*b.y; a12 += p1*b.z; a13 += p1*b.w;
        }
        qk[r0][c0+0] = a00 + ipb[j0+0]; qk[r0][c0+1] = a01 + ipb[j0+1];
        qk[r0][c0+2] = a02 + ipb[j0+2]; qk[r0][c0+3] = a03 + ipb[j0+3];
        qk[r1][c0+0] = a10 + ipb[j0+0]; qk[r1][c0+1] = a11 + ipb[j0+1];
        qk[r1][c0+2] = a12 + ipb[j0+2]; qk[r1][c0+3] = a13 + ipb[j0+3];

        if (tid < 32) {  // vw[row] = comb[row]·u_h + c_h
            float s = ch[hd];
            const float* uh = u + hd * 256;
            for (int k = 0; k < 256; ++k) s += comb[tid][k] * uh[k];
            vw[tid] = s;
        }
        __syncthreads();

        if (tid < 16) {  // per-node attention for this head
            int ra = tid * 2, rb = ra + 1;
            float s00=0,s01=0,s10=0,s11=0;
            #pragma unroll 8
            for (int d = 0; d < 32; ++d) {
                float qa = qk[ra][d],    qb = qk[rb][d];
                float ka = qk[ra][32+d], kb = qk[rb][32+d];
                s00 += qa*ka; s01 += qa*kb; s10 += qb*ka; s11 += qb*kb;
            }
            const float sc = 0.17677669529663687f;  // 1/sqrt(32)
            s00*=sc; s01*=sc; s10*=sc; s11*=sc;
            float va = vw[ra], vb = vw[rb];
            float m0 = fmaxf(s00, s01);
            float e0 = expf(s00 - m0), e1 = expf(s01 - m0);
            nodeAcc += (e0*va + e1*vb) / (e0 + e1);
            float m1 = fmaxf(s10, s11);
            float f0 = expf(s10 - m1), f1 = expf(s11 - m1);
            nodeAcc += (f0*va + f1*vb) / (f0 + f1);
        }
        __syncthreads();
    }

    if (tid < 16) red[tid] = (n0 + tid < N_NODES) ? nodeAcc : 0.0f;
    __syncthreads();
    if (tid == 0) {
        float s = 0.0f;
        for (int i = 0; i < 16; ++i) s += red[i];
        atomicAdd(accum, (double)s);
    }
}

__global__ __launch_bounds__(256) void k_final(const float* __restrict__ ow,
                                               const float* __restrict__ opb,
                                               const float* __restrict__ ob,
                                               const double* __restrict__ accum,
                                               float* __restrict__ out) {
    __shared__ float red[256];
    int tid = threadIdx.x;
    red[tid] = ow[tid] * opb[tid];
    __syncthreads();
    for (int s = 128; s > 0; s >>= 1) {
        if (tid < s) red[tid] += red[tid + s];
        __syncthreads();
    }
    if (tid == 0)
        out[0] = (float)(accum[0] / (2.0 * N_NODES) + (double)red[0] + (double)ob[0]);
}

// ---------------- launch ----------------
extern "C" void kernel_launch(void* const* d_in, const int* in_sizes, int n_in,
                              void* d_out, int out_size, void* d_ws, size_t ws_size,
                              hipStream_t stream) {
    const float* x   = (const float*)d_in[0];
    const int*   ei  = (const int*)d_in[1];
    const float* Ws  = (const float*)d_in[2];
    const float* bs  = (const float*)d_in[3];
    const float* Wf  = (const float*)d_in[4];
    const float* bf  = (const float*)d_in[5];
    const float* ipw = (const float*)d_in[6];
    const float* ipb = (const float*)d_in[7];
    const float* opw = (const float*)d_in[8];
    const float* opb = (const float*)d_in[9];
    const float* ow  = (const float*)d_in[10];
    const float* ob  = (const float*)d_in[11];
    float* out = (float*)d_out;

    if (ws_size < WS_NEED) { k_guard<<<1, 64, 0, stream>>>(out); return; }

    char* ws = (char*)d_ws;
    float*  h    = (float*)(ws + H_OFF);
    float*  agg  = (float*)(ws + AGG_OFF);
    int*    ei2  = (int*)  (ws + EI_OFF);
    int*    cnt  = (int*)  (ws + DEG_OFF);
    float*  dis  = (float*)(ws + DIS_OFF);
    float*  dinv = (float*)(ws + DINV_OFF);
    float*  Wt   = (float*)(ws + WT_OFF);
    float*  wp   = (float*)(ws + WP_OFF);
    float*  u    = (float*)(ws + U_OFF);
    float*  chv  = (float*)(ws + CH_OFF);
    int*    flag = (int*)  (ws + FLAG_OFF);
    double* accum= (double*)(ws + ACC_OFF);

    hipMemsetAsync(agg,   0, (size_t)N_NODES * 512 * 4, stream);
    hipMemsetAsync(cnt,   0, (size_t)N_NODES * 4, stream);
    hipMemsetAsync(flag,  0, 4, stream);
    hipMemsetAsync(accum, 0, 8, stream);

    k_detect<<<1, 256, 0, stream>>>(ei, flag);
    k_cvt   <<<(N_EDGES + 255) / 256, 256, 0, stream>>>(ei, flag, ei2);

    k_deg <<<(N_EDGES + 255) / 256, 256, 0, stream>>>(ei2, cnt);
    k_norm<<<(N_NODES + 255) / 256, 256, 0, stream>>>(cnt, dis, dinv);

    dim3 g3((N_NODES + 31) / 32, 8);
    k_hgemm<<<g3, 256, 0, stream>>>(x, Ws, Wf, h);

    k_edge<<<N_EDGES / 4, 256, 0, stream>>>(ei2, dis, h, agg);

    k_tr    <<<256, 256, 0, stream>>>(ipw, Wt);
    k_wprime<<<1,   256, 0, stream>>>(ow, opw, wp);
    k_u     <<<8,   256, 0, stream>>>(ipw, ipb, wp, u, chv);

    k_attn<<<(N_NODES + 15) / 16, 256, 0, stream>>>(h, agg, dinv, bs, bf, Wt, ipb, u, chv, accum);
    k_final<<<1, 256, 0, stream>>>(ow, opb, ob, accum, out);
}

// Round 3
// 1883.874 us; speedup vs baseline: 6.3013x; 6.3013x over previous
//
#include <hip/hip_runtime.h>
#include <hip/hip_bf16.h>
#include <math.h>

#define N_NODES 50000
#define N_EDGES 1600000

// ---------------- workspace layout (bytes) ----------------
static const size_t H_OFF    = 0;                        // h    [N][512] f32
static const size_t COMB_OFF = 102400000;                // comb [N][512] f32 (post-GCN, relu'd)
static const size_t CSR_OFF  = 204800000;                // int [E] src ids sorted by dst
static const size_t ROW_OFF  = 211200000;                // int [N+1] rowptr
static const size_t CNT_OFF  = 211400064;                // int [N] degree histogram
static const size_t CUR_OFF  = 211600128;                // int [N] placement cursors
static const size_t DIS_OFF  = 211800192;                // f32 [N] deg_inv_sqrt
static const size_t DINV_OFF = 212000256;                // f32 [N] 1/deg
static const size_t WT_OFF   = 212200320;                // Wt [256][768] f32 (in_proj_w^T)
static const size_t WP_OFF   = 212986752;                // w' [256]
static const size_t U_OFF    = 212987776;                // u  [8][256]
static const size_t CH_OFF   = 212995968;                // c  [8]
static const size_t FLAG_OFF = 212996224;                // int flag: 1 = int32 layout
static const size_t ACC_OFF  = 212996480;                // double accumulator
static const size_t WS_NEED  = 212996736;

// ---------------- kernels ----------------

__global__ void k_guard(float* out) { if (threadIdx.x == 0) out[0] = -12345.0f; }

// probe raw edge buffer: int64 layout has all odd int32 words == 0 (ids < 2^31)
__global__ void k_detect(const int* __restrict__ raw, int* __restrict__ flag) {
    if (raw[2 * threadIdx.x + 1] != 0) atomicOr(flag, 1);
}

__device__ __forceinline__ void load_edge(const int* raw, int is32, int e, int& s, int& d) {
    if (is32) { s = raw[e]; d = raw[N_EDGES + e]; }
    else      { s = raw[2 * (size_t)e]; d = raw[2 * ((size_t)N_EDGES + e)]; }
}

__global__ __launch_bounds__(256) void k_deg(const int* __restrict__ raw,
                                             const int* __restrict__ flag,
                                             int* __restrict__ cnt) {
    int e = blockIdx.x * 256 + threadIdx.x;
    if (e >= N_EDGES) return;
    int s, d; load_edge(raw, *flag, e, s, d);
    atomicAdd(&cnt[d], 1);
}

__global__ __launch_bounds__(256) void k_norm(const int* __restrict__ cnt,
                                              float* __restrict__ dis, float* __restrict__ dinv) {
    int n = blockIdx.x * 256 + threadIdx.x;
    if (n < N_NODES) {
        float d = 1.0f + (float)cnt[n];
        float r = rsqrtf(d);
        dis[n]  = r;
        dinv[n] = r * r;
    }
}

// exclusive scan of cnt[50000] -> rowptr[50001], single block of 1024
__global__ __launch_bounds__(1024) void k_scan(const int* __restrict__ cnt,
                                               int* __restrict__ rowptr) {
    __shared__ int part[1024];
    const int CH = 49;                       // 1024*49 = 50176 >= N_NODES
    int tid = threadIdx.x;
    int base = tid * CH;
    int s = 0;
    for (int i = 0; i < CH; ++i) {
        int idx = base + i;
        if (idx < N_NODES) s += cnt[idx];
    }
    part[tid] = s;
    __syncthreads();
    for (int off = 1; off < 1024; off <<= 1) {
        int v = (tid >= off) ? part[tid - off] : 0;
        __syncthreads();
        part[tid] += v;
        __syncthreads();
    }
    int excl = (tid == 0) ? 0 : part[tid - 1];
    for (int i = 0; i < CH; ++i) {
        int idx = base + i;
        if (idx < N_NODES) { rowptr[idx] = excl; excl += cnt[idx]; }
    }
    if (tid == 1023) rowptr[N_NODES] = excl;
}

__global__ __launch_bounds__(256) void k_place(const int* __restrict__ raw,
                                               const int* __restrict__ flag,
                                               const int* __restrict__ rowptr,
                                               int* __restrict__ cur,
                                               int* __restrict__ csr) {
    int e = blockIdx.x * 256 + threadIdx.x;
    if (e >= N_EDGES) return;
    int s, d; load_edge(raw, *flag, e, s, d);
    int pos = rowptr[d] + atomicAdd(&cur[d], 1);
    csr[pos] = s;
}

// h[n, 0:256] = x[n,0:100] @ W_s ; h[n,256:512] = x[n,100:300] @ W_f   (no bias here)
__global__ __launch_bounds__(256) void k_hgemm(const float* __restrict__ x,
                                               const float* __restrict__ Ws,
                                               const float* __restrict__ Wf,
                                               float* __restrict__ h) {
    __shared__ float xs[32][201];
    int tid  = threadIdx.x;
    int n0   = blockIdx.x * 32;
    int half = blockIdx.y >> 2;          // 0: s-features, 1: f-features
    int cg   = blockIdx.y & 3;           // column group of 64
    int K    = half ? 200 : 100;
    int xoff = half ? 100 : 0;
    const float* W = half ? Wf : Ws;
    int base = half ? 256 : 0;

    for (int idx = tid; idx < 32 * K; idx += 256) {
        int nd = idx / K, kk = idx - nd * K;
        int n = n0 + nd;
        xs[nd][kk] = (n < N_NODES) ? x[(size_t)n * 300 + xoff + kk] : 0.0f;
    }
    __syncthreads();

    int cgrp = tid & 15, rgrp = tid >> 4;
    int c0 = cg * 64 + cgrp * 4;
    int r0 = rgrp * 2, r1 = r0 + 1;
    float a00=0,a01=0,a02=0,a03=0, a10=0,a11=0,a12=0,a13=0;
    for (int k = 0; k < K; ++k) {
        float4 b = *reinterpret_cast<const float4*>(&W[k * 256 + c0]);
        float p0 = xs[r0][k], p1 = xs[r1][k];
        a00 += p0*b.x; a01 += p0*b.y; a02 += p0*b.z; a03 += p0*b.w;
        a10 += p1*b.x; a11 += p1*b.y; a12 += p1*b.z; a13 += p1*b.w;
    }
    int n_a = n0 + r0, n_b = n0 + r1;
    if (n_a < N_NODES) {
        float4 v = make_float4(a00,a01,a02,a03);
        *reinterpret_cast<float4*>(&h[(size_t)n_a * 512 + base + c0]) = v;
    }
    if (n_b < N_NODES) {
        float4 v = make_float4(a10,a11,a12,a13);
        *reinterpret_cast<float4*>(&h[(size_t)n_b * 512 + base + c0]) = v;
    }
}

// one wave per dst node: comb[n] = relu(dis[n]*sum_e dis[src]*h[src] + dinv[n]*h[n] + bias)
__global__ __launch_bounds__(256) void k_agg(const int* __restrict__ csr,
                                             const int* __restrict__ rowptr,
                                             const float* __restrict__ dis,
                                             const float* __restrict__ dinv,
                                             const float* __restrict__ h,
                                             const float* __restrict__ bs,
                                             const float* __restrict__ bf,
                                             float* __restrict__ comb) {
    int n    = blockIdx.x * 4 + (threadIdx.x >> 6);
    int lane = threadIdx.x & 63;
    if (n >= N_NODES) return;
    int beg = rowptr[n], end = rowptr[n + 1];
    float4 a0 = make_float4(0,0,0,0), a1 = make_float4(0,0,0,0);
    for (int e = beg; e < end; ++e) {
        int s = csr[e];
        float c = dis[s];
        const float4* hs = reinterpret_cast<const float4*>(h + (size_t)s * 512);
        float4 v0 = hs[lane];
        float4 v1 = hs[lane + 64];
        a0.x += c*v0.x; a0.y += c*v0.y; a0.z += c*v0.z; a0.w += c*v0.w;
        a1.x += c*v1.x; a1.y += c*v1.y; a1.z += c*v1.z; a1.w += c*v1.w;
    }
    float dn = dis[n], di = dinv[n];
    const float4* hn = reinterpret_cast<const float4*>(h + (size_t)n * 512);
    float4 h0 = hn[lane], h1 = hn[lane + 64];
    float4 b0 = reinterpret_cast<const float4*>(bs)[lane];      // token0 ch 4*lane
    float4 b1 = reinterpret_cast<const float4*>(bf)[lane];      // token1 ch 4*lane
    float4 r0, r1;
    r0.x = fmaxf(dn*a0.x + di*h0.x + b0.x, 0.0f);
    r0.y = fmaxf(dn*a0.y + di*h0.y + b0.y, 0.0f);
    r0.z = fmaxf(dn*a0.z + di*h0.z + b0.z, 0.0f);
    r0.w = fmaxf(dn*a0.w + di*h0.w + b0.w, 0.0f);
    r1.x = fmaxf(dn*a1.x + di*h1.x + b1.x, 0.0f);
    r1.y = fmaxf(dn*a1.y + di*h1.y + b1.y, 0.0f);
    r1.z = fmaxf(dn*a1.z + di*h1.z + b1.z, 0.0f);
    r1.w = fmaxf(dn*a1.w + di*h1.w + b1.w, 0.0f);
    float4* cp = reinterpret_cast<float4*>(comb + (size_t)n * 512);
    cp[lane]      = r0;
    cp[lane + 64] = r1;
}

// Wt[k][j] = in_proj_w[j][k]
__global__ __launch_bounds__(256) void k_tr(const float* __restrict__ ipw, float* __restrict__ Wt) {
    int k = blockIdx.x;
    for (int j = threadIdx.x; j < 768; j += 256)
        Wt[k * 768 + j] = ipw[(size_t)j * 256 + k];
}

// w'[i] = sum_j out_w[j] * out_proj_w[j][i]
__global__ __launch_bounds__(256) void k_wprime(const float* __restrict__ ow,
                                                const float* __restrict__ opw,
                                                float* __restrict__ wp) {
    int i = threadIdx.x;
    float s = 0.0f;
    for (int j = 0; j < 256; ++j) s += ow[j] * opw[j * 256 + i];
    wp[i] = s;
}

// u[h][i] = sum_d ipw[512+h*32+d][i] * w'[h*32+d] ;  c[h] = sum_d ipb[512+h*32+d]*w'[h*32+d]
__global__ __launch_bounds__(256) void k_u(const float* __restrict__ ipw,
                                           const float* __restrict__ ipb,
                                           const float* __restrict__ wp,
                                           float* __restrict__ u, float* __restrict__ ch) {
    int hd = blockIdx.x, i = threadIdx.x;
    float s = 0.0f;
    for (int d = 0; d < 32; ++d)
        s += ipw[(size_t)(512 + hd * 32 + d) * 256 + i] * wp[hd * 32 + d];
    u[hd * 256 + i] = s;
    if (i == 0) {
        float c = 0.0f;
        for (int d = 0; d < 32; ++d) c += ipb[512 + hd * 32 + d] * wp[hd * 32 + d];
        ch[hd] = c;
    }
}

// fused: per-head q/k GEMM on comb -> softmax -> vw combine -> reduce
__global__ __launch_bounds__(256) void k_attn(const float* __restrict__ comb_g,
                                              const float* __restrict__ Wt,
                                              const float* __restrict__ ipb,
                                              const float* __restrict__ u,
                                              const float* __restrict__ ch,
                                              double* __restrict__ accum) {
    __shared__ float comb[32][257];   // 16 nodes x 2 tokens, padded
    __shared__ float qk[32][65];      // cols 0..31 q, 32..63 k, padded
    __shared__ float vw[32];
    __shared__ float red[16];

    int tid = threadIdx.x;
    int n0  = blockIdx.x * 16;

    for (int idx = tid; idx < 32 * 256; idx += 256) {
        int row = idx >> 8, j = idx & 255;
        int n = n0 + (row >> 1), t = row & 1;
        comb[row][j] = (n < N_NODES) ? comb_g[(size_t)n * 512 + t * 256 + j] : 0.0f;
    }
    __syncthreads();

    int cgrp = tid & 15, rgrp = tid >> 4;
    int c0 = cgrp * 4;
    int r0 = rgrp * 2, r1 = r0 + 1;
    float nodeAcc = 0.0f;

    for (int hd = 0; hd < 8; ++hd) {
        int j0 = (c0 < 32) ? (hd * 32 + c0) : (256 + hd * 32 + (c0 - 32));
        float a00=0,a01=0,a02=0,a03=0, a10=0,a11=0,a12=0,a13=0;
        for (int k = 0; k < 256; ++k) {
            float4 b = *reinterpret_cast<const float4*>(&Wt[k * 768 + j0]);
            float p0 = comb[r0][k], p1 = comb[r1][k];
            a00 += p0*b.x; a01 += p0*b.y; a02 += p0*b.z; a03 += p0*b.w;
            a10 += p1*b.x; a11 += p1*b.y; a12 += p1*b.z; a13 += p1*b.w;
        }
        qk[r0][c0+0] = a00 + ipb[j0+0]; qk[r0][c0+1] = a01 + ipb[j0+1];
        qk[r0][c0+2] = a02 + ipb[j0+2]; qk[r0][c0+3] = a03 + ipb[j0+3];
        qk[r1][c0+0] = a10 + ipb[j0+0]; qk[r1][c0+1] = a11 + ipb[j0+1];
        qk[r1][c0+2] = a12 + ipb[j0+2]; qk[r1][c0+3] = a13 + ipb[j0+3];

        if (tid < 32) {  // vw[row] = comb[row]·u_h + c_h
            float s = ch[hd];
            const float* uh = u + hd * 256;
            for (int k = 0; k < 256; ++k) s += comb[tid][k] * uh[k];
            vw[tid] = s;
        }
        __syncthreads();

        if (tid < 16) {  // per-node attention for this head
            int ra = tid * 2, rb = ra + 1;
            float s00=0,s01=0,s10=0,s11=0;
            #pragma unroll 8
            for (int d = 0; d < 32; ++d) {
                float qa = qk[ra][d],    qb = qk[rb][d];
                float ka = qk[ra][32+d], kb = qk[rb][32+d];
                s00 += qa*ka; s01 += qa*kb; s10 += qb*ka; s11 += qb*kb;
            }
            const float sc = 0.17677669529663687f;  // 1/sqrt(32)
            s00*=sc; s01*=sc; s10*=sc; s11*=sc;
            float va = vw[ra], vb = vw[rb];
            float m0 = fmaxf(s00, s01);
            float e0 = expf(s00 - m0), e1 = expf(s01 - m0);
            nodeAcc += (e0*va + e1*vb) / (e0 + e1);
            float m1 = fmaxf(s10, s11);
            float f0 = expf(s10 - m1), f1 = expf(s11 - m1);
            nodeAcc += (f0*va + f1*vb) / (f0 + f1);
        }
        __syncthreads();
    }

    if (tid < 16) red[tid] = (n0 + tid < N_NODES) ? nodeAcc : 0.0f;
    __syncthreads();
    if (tid == 0) {
        float s = 0.0f;
        for (int i = 0; i < 16; ++i) s += red[i];
        atomicAdd(accum, (double)s);
    }
}

__global__ __launch_bounds__(256) void k_final(const float* __restrict__ ow,
                                               const float* __restrict__ opb,
                                               const float* __restrict__ ob,
                                               const double* __restrict__ accum,
                                               float* __restrict__ out) {
    __shared__ float red[256];
    int tid = threadIdx.x;
    red[tid] = ow[tid] * opb[tid];
    __syncthreads();
    for (int s = 128; s > 0; s >>= 1) {
        if (tid < s) red[tid] += red[tid + s];
        __syncthreads();
    }
    if (tid == 0)
        out[0] = (float)(accum[0] / (2.0 * N_NODES) + (double)red[0] + (double)ob[0]);
}

// ---------------- launch ----------------
extern "C" void kernel_launch(void* const* d_in, const int* in_sizes, int n_in,
                              void* d_out, int out_size, void* d_ws, size_t ws_size,
                              hipStream_t stream) {
    const float* x   = (const float*)d_in[0];
    const int*   ei  = (const int*)d_in[1];
    const float* Ws  = (const float*)d_in[2];
    const float* bs  = (const float*)d_in[3];
    const float* Wf  = (const float*)d_in[4];
    const float* bf  = (const float*)d_in[5];
    const float* ipw = (const float*)d_in[6];
    const float* ipb = (const float*)d_in[7];
    const float* opw = (const float*)d_in[8];
    const float* opb = (const float*)d_in[9];
    const float* ow  = (const float*)d_in[10];
    const float* ob  = (const float*)d_in[11];
    float* out = (float*)d_out;

    if (ws_size < WS_NEED) { k_guard<<<1, 64, 0, stream>>>(out); return; }

    char* ws = (char*)d_ws;
    float*  h    = (float*)(ws + H_OFF);
    float*  comb = (float*)(ws + COMB_OFF);
    int*    csr  = (int*)  (ws + CSR_OFF);
    int*    row  = (int*)  (ws + ROW_OFF);
    int*    cnt  = (int*)  (ws + CNT_OFF);
    int*    cur  = (int*)  (ws + CUR_OFF);
    float*  dis  = (float*)(ws + DIS_OFF);
    float*  dinv = (float*)(ws + DINV_OFF);
    float*  Wt   = (float*)(ws + WT_OFF);
    float*  wp   = (float*)(ws + WP_OFF);
    float*  u    = (float*)(ws + U_OFF);
    float*  chv  = (float*)(ws + CH_OFF);
    int*    flag = (int*)  (ws + FLAG_OFF);
    double* accum= (double*)(ws + ACC_OFF);

    hipMemsetAsync(cnt,   0, (size_t)N_NODES * 4, stream);
    hipMemsetAsync(cur,   0, (size_t)N_NODES * 4, stream);
    hipMemsetAsync(flag,  0, 4, stream);
    hipMemsetAsync(accum, 0, 8, stream);

    k_detect<<<1, 256, 0, stream>>>(ei, flag);
    k_deg   <<<(N_EDGES + 255) / 256, 256, 0, stream>>>(ei, flag, cnt);
    k_norm  <<<(N_NODES + 255) / 256, 256, 0, stream>>>(cnt, dis, dinv);
    k_scan  <<<1, 1024, 0, stream>>>(cnt, row);
    k_place <<<(N_EDGES + 255) / 256, 256, 0, stream>>>(ei, flag, row, cur, csr);

    dim3 g3((N_NODES + 31) / 32, 8);
    k_hgemm<<<g3, 256, 0, stream>>>(x, Ws, Wf, h);

    k_agg<<<(N_NODES + 3) / 4, 256, 0, stream>>>(csr, row, dis, dinv, h, bs, bf, comb);

    k_tr    <<<256, 256, 0, stream>>>(ipw, Wt);
    k_wprime<<<1,   256, 0, stream>>>(ow, opw, wp);
    k_u     <<<8,   256, 0, stream>>>(ipw, ipb, wp, u, chv);

    k_attn<<<(N_NODES + 15) / 16, 256, 0, stream>>>(comb, Wt, ipb, u, chv, accum);
    k_final<<<1, 256, 0, stream>>>(ow, opb, ob, accum, out);
}

// Round 4
// 1154.894 us; speedup vs baseline: 10.2787x; 1.6312x over previous
//
#include <hip/hip_runtime.h>
#include <hip/hip_bf16.h>
#include <math.h>

#define N_NODES 50000
#define N_EDGES 1600000
#define M_ROWS  100000   // 2 tokens per node

// ---------------- workspace layout (bytes) ----------------
// Lifetimes: h, csr die after k_agg; C (written by k_qkv) overlaps them.
static const size_t H_OFF    = 0;                 // h bf16 [50000][512] = 51,200,000
static const size_t CSR_OFF  = 51200000;          // int [E] = 6,400,000 -> 57,600,000
static const size_t C_OFF    = 0;                 // C bf16 [100000][520] = 104,000,000 (after h/csr dead)
static const size_t COMB_OFF = 104000000;         // bf16 [100000][256] = 51,200,000 -> 155,200,000
static const size_t ROW_OFF  = 155200000;         // int [N+1]
static const size_t CNT_OFF  = 155400064;         // int [N]
static const size_t CUR_OFF  = 155600128;         // int [N]
static const size_t DIS_OFF  = 155800192;         // f32 [N]
static const size_t DINV_OFF = 156000256;         // f32 [N]
static const size_t BT_OFF   = 156200320;         // bf16 [576][256] = 294,912
static const size_t B2_OFF   = 156495232;         // f32 [576]
static const size_t WP_OFF   = 156497536;         // f32 [256]
static const size_t U_OFF    = 156498560;         // f32 [8][256]
static const size_t CH_OFF   = 156506752;         // f32 [8]
static const size_t FLAG_OFF = 156506816;         // int
static const size_t ACC_OFF  = 156506880;         // double
static const size_t WS_NEED  = 156506944;

typedef __attribute__((ext_vector_type(8))) short short8v;
typedef __attribute__((ext_vector_type(4))) float f32x4;

__device__ __forceinline__ float bf_lo(unsigned int u) { return __uint_as_float(u << 16); }
__device__ __forceinline__ float bf_hi(unsigned int u) { return __uint_as_float(u & 0xffff0000u); }
__device__ __forceinline__ unsigned short f2bf(float f) {
    unsigned int x = __float_as_uint(f);
    return (unsigned short)((x + 0x7fffu + ((x >> 16) & 1u)) >> 16);   // RNE
}

// ---------------- kernels ----------------

__global__ void k_guard(float* out) { if (threadIdx.x == 0) out[0] = -12345.0f; }

// probe raw edge buffer: int64 layout has all odd int32 words == 0 (ids < 2^31)
__global__ void k_detect(const int* __restrict__ raw, int* __restrict__ flag) {
    if (raw[2 * threadIdx.x + 1] != 0) atomicOr(flag, 1);
}

__device__ __forceinline__ void load_edge(const int* raw, int is32, int e, int& s, int& d) {
    if (is32) { s = raw[e]; d = raw[N_EDGES + e]; }
    else      { s = raw[2 * (size_t)e]; d = raw[2 * ((size_t)N_EDGES + e)]; }
}

__global__ __launch_bounds__(256) void k_deg(const int* __restrict__ raw,
                                             const int* __restrict__ flag,
                                             int* __restrict__ cnt) {
    int e = blockIdx.x * 256 + threadIdx.x;
    if (e >= N_EDGES) return;
    int s, d; load_edge(raw, *flag, e, s, d);
    atomicAdd(&cnt[d], 1);
}

__global__ __launch_bounds__(256) void k_norm(const int* __restrict__ cnt,
                                              float* __restrict__ dis, float* __restrict__ dinv) {
    int n = blockIdx.x * 256 + threadIdx.x;
    if (n < N_NODES) {
        float d = 1.0f + (float)cnt[n];
        float r = rsqrtf(d);
        dis[n]  = r;
        dinv[n] = r * r;
    }
}

// exclusive scan of cnt[50000] -> rowptr[50001], single block of 1024
__global__ __launch_bounds__(1024) void k_scan(const int* __restrict__ cnt,
                                               int* __restrict__ rowptr) {
    __shared__ int part[1024];
    const int CH = 49;
    int tid = threadIdx.x;
    int base = tid * CH;
    int s = 0;
    for (int i = 0; i < CH; ++i) {
        int idx = base + i;
        if (idx < N_NODES) s += cnt[idx];
    }
    part[tid] = s;
    __syncthreads();
    for (int off = 1; off < 1024; off <<= 1) {
        int v = (tid >= off) ? part[tid - off] : 0;
        __syncthreads();
        part[tid] += v;
        __syncthreads();
    }
    int excl = (tid == 0) ? 0 : part[tid - 1];
    for (int i = 0; i < CH; ++i) {
        int idx = base + i;
        if (idx < N_NODES) { rowptr[idx] = excl; excl += cnt[idx]; }
    }
    if (tid == 1023) rowptr[N_NODES] = excl;
}

__global__ __launch_bounds__(256) void k_place(const int* __restrict__ raw,
                                               const int* __restrict__ flag,
                                               const int* __restrict__ rowptr,
                                               int* __restrict__ cur,
                                               int* __restrict__ csr) {
    int e = blockIdx.x * 256 + threadIdx.x;
    if (e >= N_EDGES) return;
    int s, d; load_edge(raw, *flag, e, s, d);
    int pos = rowptr[d] + atomicAdd(&cur[d], 1);
    csr[pos] = s;
}

// h[n, 0:256] = x[n,0:100] @ W_s ; h[n,256:512] = x[n,100:300] @ W_f  (bf16 store)
__global__ __launch_bounds__(256) void k_hgemm(const float* __restrict__ x,
                                               const float* __restrict__ Ws,
                                               const float* __restrict__ Wf,
                                               unsigned short* __restrict__ h) {
    __shared__ float xs[32][201];
    __shared__ float sW[50][64];
    int tid  = threadIdx.x;
    int n0   = blockIdx.x * 32;
    int half = blockIdx.y >> 2;
    int cg   = blockIdx.y & 3;
    int K    = half ? 200 : 100;
    int xoff = half ? 100 : 0;
    const float* W = half ? Wf : Ws;
    int base = half ? 256 : 0;

    for (int idx = tid; idx < 32 * K; idx += 256) {
        int nd = idx / K, kk = idx - nd * K;
        int n = n0 + nd;
        xs[nd][kk] = (n < N_NODES) ? x[(size_t)n * 300 + xoff + kk] : 0.0f;
    }

    int cgrp = tid & 15, rgrp = tid >> 4;
    int c0loc = cgrp * 4;                 // column within the 64-col group
    int c0 = cg * 64 + c0loc;
    int r0 = rgrp * 2, r1 = r0 + 1;
    float a00=0,a01=0,a02=0,a03=0, a10=0,a11=0,a12=0,a13=0;

    for (int kc = 0; kc < K; kc += 50) {
        __syncthreads();
        for (int idx = tid; idx < 50 * 64; idx += 256) {
            int kk = idx >> 6, cc = idx & 63;
            sW[kk][cc] = W[(size_t)(kc + kk) * 256 + cg * 64 + cc];
        }
        __syncthreads();
        for (int kk = 0; kk < 50; ++kk) {
            float4 b = *reinterpret_cast<const float4*>(&sW[kk][c0loc]);
            float p0 = xs[r0][kc + kk], p1 = xs[r1][kc + kk];
            a00 += p0*b.x; a01 += p0*b.y; a02 += p0*b.z; a03 += p0*b.w;
            a10 += p1*b.x; a11 += p1*b.y; a12 += p1*b.z; a13 += p1*b.w;
        }
    }
    int n_a = n0 + r0, n_b = n0 + r1;
    if (n_a < N_NODES) {
        ushort4 v; v.x = f2bf(a00); v.y = f2bf(a01); v.z = f2bf(a02); v.w = f2bf(a03);
        *reinterpret_cast<ushort4*>(&h[(size_t)n_a * 512 + base + c0]) = v;
    }
    if (n_b < N_NODES) {
        ushort4 v; v.x = f2bf(a10); v.y = f2bf(a11); v.z = f2bf(a12); v.w = f2bf(a13);
        *reinterpret_cast<ushort4*>(&h[(size_t)n_b * 512 + base + c0]) = v;
    }
}

// one wave per dst node: comb rows 2n (ch 0..255) / 2n+1 (ch 256..511), bf16
__global__ __launch_bounds__(256) void k_agg(const int* __restrict__ csr,
                                             const int* __restrict__ rowptr,
                                             const float* __restrict__ dis,
                                             const float* __restrict__ dinv,
                                             const unsigned short* __restrict__ h,
                                             const float* __restrict__ bs,
                                             const float* __restrict__ bf,
                                             unsigned short* __restrict__ comb) {
    int n    = blockIdx.x * 4 + (threadIdx.x >> 6);
    int lane = threadIdx.x & 63;
    if (n >= N_NODES) return;
    int beg = rowptr[n], end = rowptr[n + 1];
    float a0=0,a1=0,a2=0,a3=0,a4=0,a5=0,a6=0,a7=0;
    for (int e = beg; e < end; ++e) {
        int s = csr[e];
        float c = dis[s];
        uint4 v = *reinterpret_cast<const uint4*>(h + (size_t)s * 512 + lane * 8);
        a0 += c * bf_lo(v.x); a1 += c * bf_hi(v.x);
        a2 += c * bf_lo(v.y); a3 += c * bf_hi(v.y);
        a4 += c * bf_lo(v.z); a5 += c * bf_hi(v.z);
        a6 += c * bf_lo(v.w); a7 += c * bf_hi(v.w);
    }
    float dn = dis[n], di = dinv[n];
    uint4 hv = *reinterpret_cast<const uint4*>(h + (size_t)n * 512 + lane * 8);
    int j0 = lane * 8;
    const float* bp = (lane < 32) ? (bs + j0) : (bf + (j0 - 256));
    float r0 = fmaxf(dn*a0 + di*bf_lo(hv.x) + bp[0], 0.0f);
    float r1 = fmaxf(dn*a1 + di*bf_hi(hv.x) + bp[1], 0.0f);
    float r2 = fmaxf(dn*a2 + di*bf_lo(hv.y) + bp[2], 0.0f);
    float r3 = fmaxf(dn*a3 + di*bf_hi(hv.y) + bp[3], 0.0f);
    float r4 = fmaxf(dn*a4 + di*bf_lo(hv.z) + bp[4], 0.0f);
    float r5 = fmaxf(dn*a5 + di*bf_hi(hv.z) + bp[5], 0.0f);
    float r6 = fmaxf(dn*a6 + di*bf_lo(hv.w) + bp[6], 0.0f);
    float r7 = fmaxf(dn*a7 + di*bf_hi(hv.w) + bp[7], 0.0f);
    uint4 o;
    o.x = (unsigned int)f2bf(r0) | ((unsigned int)f2bf(r1) << 16);
    o.y = (unsigned int)f2bf(r2) | ((unsigned int)f2bf(r3) << 16);
    o.z = (unsigned int)f2bf(r4) | ((unsigned int)f2bf(r5) << 16);
    o.w = (unsigned int)f2bf(r6) | ((unsigned int)f2bf(r7) << 16);
    int row = 2 * n + (lane >> 5);
    int colb = (lane * 8) & 255;
    *reinterpret_cast<uint4*>(comb + (size_t)row * 256 + colb) = o;
}

// w'[i] = sum_j out_w[j] * out_proj_w[j][i]
__global__ __launch_bounds__(256) void k_wprime(const float* __restrict__ ow,
                                                const float* __restrict__ opw,
                                                float* __restrict__ wp) {
    int i = threadIdx.x;
    float s = 0.0f;
    for (int j = 0; j < 256; ++j) s += ow[j] * opw[j * 256 + i];
    wp[i] = s;
}

// u[h][i] = sum_d ipw[512+h*32+d][i] * w'[h*32+d] ;  c[h] = sum_d ipb[...]*w'[...]
__global__ __launch_bounds__(256) void k_u(const float* __restrict__ ipw,
                                           const float* __restrict__ ipb,
                                           const float* __restrict__ wp,
                                           float* __restrict__ u, float* __restrict__ ch) {
    int hd = blockIdx.x, i = threadIdx.x;
    float s = 0.0f;
    for (int d = 0; d < 32; ++d)
        s += ipw[(size_t)(512 + hd * 32 + d) * 256 + i] * wp[hd * 32 + d];
    u[hd * 256 + i] = s;
    if (i == 0) {
        float c = 0.0f;
        for (int d = 0; d < 32; ++d) c += ipb[512 + hd * 32 + d] * wp[hd * 32 + d];
        ch[hd] = c;
    }
}

// Bt[j][k] bf16: j<512 -> ipw[j][k] (q,k weights); 512..519 -> u[j-512][k]; else 0.
// b2[j]: j<512 -> ipb[j]; 512..519 -> ch[j-512]; else 0.
__global__ __launch_bounds__(256) void k_makeB(const float* __restrict__ ipw,
                                               const float* __restrict__ ipb,
                                               const float* __restrict__ u,
                                               const float* __restrict__ ch,
                                               unsigned short* __restrict__ Bt,
                                               float* __restrict__ b2) {
    int j = blockIdx.x, k = threadIdx.x;
    float v = 0.0f;
    if (j < 512)      v = ipw[(size_t)j * 256 + k];
    else if (j < 520) v = u[(j - 512) * 256 + k];
    Bt[(size_t)j * 256 + k] = f2bf(v);
    if (k == 0) b2[j] = (j < 512) ? ipb[j] : ((j < 520) ? ch[j - 512] : 0.0f);
}

// MFMA GEMM: C[M=100032][N=576] = comb[M][256] @ Bt^T, bias b2, bf16 out (col<520, row<100000)
__global__ __launch_bounds__(256) void k_qkv(const unsigned short* __restrict__ comb,
                                             const unsigned short* __restrict__ Bt,
                                             const float* __restrict__ b2,
                                             unsigned short* __restrict__ C) {
    __shared__ __align__(16) unsigned short sA[64][40];   // 64 rows x 32 k, pad->40
    __shared__ __align__(16) unsigned short sB[64][40];   // 64 cols x 32 k, pad->40
    int tid  = threadIdx.x;
    int lane = tid & 63, wid = tid >> 6;
    int wm = wid >> 1, wn = wid & 1;                      // 2x2 wave grid
    int arow = tid >> 2, aseg = (tid & 3) * 8;            // staging coords
    long grow = (long)blockIdx.x * 64 + arow;
    bool aval = grow < M_ROWS;
    const unsigned short* aptr = comb + grow * 256 + aseg;
    const unsigned short* bptr = Bt + ((long)blockIdx.y * 64 + arow) * 256 + aseg;

    f32x4 acc00 = {0,0,0,0}, acc01 = {0,0,0,0}, acc10 = {0,0,0,0}, acc11 = {0,0,0,0};
    int fr = lane & 15, fk = (lane >> 4) * 8;

    for (int ks = 0; ks < 8; ++ks) {
        uint4 av = aval ? *reinterpret_cast<const uint4*>(aptr + ks * 32) : make_uint4(0,0,0,0);
        uint4 bv = *reinterpret_cast<const uint4*>(bptr + ks * 32);
        __syncthreads();
        *reinterpret_cast<uint4*>(&sA[arow][aseg]) = av;
        *reinterpret_cast<uint4*>(&sB[arow][aseg]) = bv;
        __syncthreads();
        short8v a0 = *reinterpret_cast<const short8v*>(&sA[wm * 32 + fr][fk]);
        short8v a1 = *reinterpret_cast<const short8v*>(&sA[wm * 32 + 16 + fr][fk]);
        short8v b0 = *reinterpret_cast<const short8v*>(&sB[wn * 32 + fr][fk]);
        short8v b1 = *reinterpret_cast<const short8v*>(&sB[wn * 32 + 16 + fr][fk]);
        acc00 = __builtin_amdgcn_mfma_f32_16x16x32_bf16(a0, b0, acc00, 0, 0, 0);
        acc01 = __builtin_amdgcn_mfma_f32_16x16x32_bf16(a0, b1, acc01, 0, 0, 0);
        acc10 = __builtin_amdgcn_mfma_f32_16x16x32_bf16(a1, b0, acc10, 0, 0, 0);
        acc11 = __builtin_amdgcn_mfma_f32_16x16x32_bf16(a1, b1, acc11, 0, 0, 0);
    }

    // epilogue: C/D layout col=lane&15, row=(lane>>4)*4+j
    int crow = blockIdx.x * 64 + wm * 32;
    int ccol = blockIdx.y * 64 + wn * 32;
    int rb = (lane >> 4) * 4;
    #pragma unroll
    for (int mn = 0; mn < 4; ++mn) {
        int m = mn >> 1, nn = mn & 1;
        f32x4 a = (mn == 0) ? acc00 : (mn == 1) ? acc01 : (mn == 2) ? acc10 : acc11;
        int col = ccol + nn * 16 + (lane & 15);
        if (col < 520) {
            float bias = b2[col];
            #pragma unroll
            for (int j = 0; j < 4; ++j) {
                int row = crow + m * 16 + rb + j;
                if (row < M_ROWS) C[(size_t)row * 520 + col] = f2bf(a[j] + bias);
            }
        }
    }
}

// finalize: wave per node; scores+softmax+vw combine; block -> f64 atomic
__global__ __launch_bounds__(256) void k_att(const unsigned short* __restrict__ C,
                                             double* __restrict__ accum) {
    __shared__ float sQK[4][2][536];   // padded: elem e stored at e + (e>>5)
    __shared__ float red[4];
    int tid = threadIdx.x;
    int lane = tid & 63, wid = tid >> 6;
    int n = blockIdx.x * 4 + wid;

    if (n < N_NODES) {
        for (int c = lane; c < 130; c += 64) {
            int r = (c >= 65), co = c - r * 65;
            int off = co * 8;
            uint4 v = *reinterpret_cast<const uint4*>(C + ((size_t)(2 * n + r) * 520 + off));
            float f0 = bf_lo(v.x), f1 = bf_hi(v.x), f2 = bf_lo(v.y), f3 = bf_hi(v.y);
            float f4 = bf_lo(v.z), f5 = bf_hi(v.z), f6 = bf_lo(v.w), f7 = bf_hi(v.w);
            float* dst = &sQK[wid][r][0];
            dst[(off+0) + ((off+0)>>5)] = f0; dst[(off+1) + ((off+1)>>5)] = f1;
            dst[(off+2) + ((off+2)>>5)] = f2; dst[(off+3) + ((off+3)>>5)] = f3;
            dst[(off+4) + ((off+4)>>5)] = f4; dst[(off+5) + ((off+5)>>5)] = f5;
            dst[(off+6) + ((off+6)>>5)] = f6; dst[(off+7) + ((off+7)>>5)] = f7;
        }
    }
    __syncthreads();

    float acc = 0.0f;
    if (lane < 32 && n < N_NODES) {
        int hd = lane >> 2, t = (lane >> 1) & 1, t2 = lane & 1;
        const float* Q  = &sQK[wid][t][0];
        const float* K2 = &sQK[wid][t2][0];
        int qb = 33 * hd;          // (hd*32+d) + hd
        int kb = 264 + 33 * hd;    // (256+hd*32+d) + 8 + hd
        float s = 0.0f;
        #pragma unroll 8
        for (int d = 0; d < 32; ++d) s += Q[qb + d] * K2[kb + d];
        s *= 0.17677669529663687f; // 1/sqrt(32)
        float so = __shfl_xor(s, 1);
        float m  = fmaxf(s, so);
        float e  = expf(s - m), eo = expf(so - m);
        float w  = e / (e + eo);
        acc = w * K2[528 + hd];    // vw[t2][hd] at elem 512+hd -> 528+hd
    }
    #pragma unroll
    for (int off = 1; off < 32; off <<= 1) acc += __shfl_xor(acc, off);
    if (lane == 0) red[wid] = acc;
    __syncthreads();
    if (tid == 0) atomicAdd(accum, (double)(red[0] + red[1] + red[2] + red[3]));
}

__global__ __launch_bounds__(256) void k_final(const float* __restrict__ ow,
                                               const float* __restrict__ opb,
                                               const float* __restrict__ ob,
                                               const double* __restrict__ accum,
                                               float* __restrict__ out) {
    __shared__ float red[256];
    int tid = threadIdx.x;
    red[tid] = ow[tid] * opb[tid];
    __syncthreads();
    for (int s = 128; s > 0; s >>= 1) {
        if (tid < s) red[tid] += red[tid + s];
        __syncthreads();
    }
    if (tid == 0)
        out[0] = (float)(accum[0] / (2.0 * N_NODES) + (double)red[0] + (double)ob[0]);
}

// ---------------- launch ----------------
extern "C" void kernel_launch(void* const* d_in, const int* in_sizes, int n_in,
                              void* d_out, int out_size, void* d_ws, size_t ws_size,
                              hipStream_t stream) {
    const float* x   = (const float*)d_in[0];
    const int*   ei  = (const int*)d_in[1];
    const float* Ws  = (const float*)d_in[2];
    const float* bs  = (const float*)d_in[3];
    const float* Wf  = (const float*)d_in[4];
    const float* bf  = (const float*)d_in[5];
    const float* ipw = (const float*)d_in[6];
    const float* ipb = (const float*)d_in[7];
    const float* opw = (const float*)d_in[8];
    const float* opb = (const float*)d_in[9];
    const float* ow  = (const float*)d_in[10];
    const float* ob  = (const float*)d_in[11];
    float* out = (float*)d_out;

    if (ws_size < WS_NEED) { k_guard<<<1, 64, 0, stream>>>(out); return; }

    char* ws = (char*)d_ws;
    unsigned short* h    = (unsigned short*)(ws + H_OFF);
    int*            csr  = (int*)           (ws + CSR_OFF);
    unsigned short* C    = (unsigned short*)(ws + C_OFF);
    unsigned short* comb = (unsigned short*)(ws + COMB_OFF);
    int*            row  = (int*)           (ws + ROW_OFF);
    int*            cnt  = (int*)           (ws + CNT_OFF);
    int*            cur  = (int*)           (ws + CUR_OFF);
    float*          dis  = (float*)         (ws + DIS_OFF);
    float*          dinv = (float*)         (ws + DINV_OFF);
    unsigned short* Bt   = (unsigned short*)(ws + BT_OFF);
    float*          b2   = (float*)         (ws + B2_OFF);
    float*          wp   = (float*)         (ws + WP_OFF);
    float*          u    = (float*)         (ws + U_OFF);
    float*          chv  = (float*)         (ws + CH_OFF);
    int*            flag = (int*)           (ws + FLAG_OFF);
    double*         accum= (double*)        (ws + ACC_OFF);

    hipMemsetAsync(cnt,   0, (size_t)N_NODES * 4, stream);
    hipMemsetAsync(cur,   0, (size_t)N_NODES * 4, stream);
    hipMemsetAsync(flag,  0, 4, stream);
    hipMemsetAsync(accum, 0, 8, stream);

    k_detect<<<1, 256, 0, stream>>>(ei, flag);
    k_deg   <<<(N_EDGES + 255) / 256, 256, 0, stream>>>(ei, flag, cnt);
    k_norm  <<<(N_NODES + 255) / 256, 256, 0, stream>>>(cnt, dis, dinv);
    k_scan  <<<1, 1024, 0, stream>>>(cnt, row);
    k_place <<<(N_EDGES + 255) / 256, 256, 0, stream>>>(ei, flag, row, cur, csr);

    dim3 g3((N_NODES + 31) / 32, 8);
    k_hgemm<<<g3, 256, 0, stream>>>(x, Ws, Wf, h);

    k_agg<<<(N_NODES + 3) / 4, 256, 0, stream>>>(csr, row, dis, dinv, h, bs, bf, comb);

    k_wprime<<<1,   256, 0, stream>>>(ow, opw, wp);
    k_u     <<<8,   256, 0, stream>>>(ipw, ipb, wp, u, chv);
    k_makeB <<<576, 256, 0, stream>>>(ipw, ipb, u, chv, Bt, b2);

    dim3 gq((M_ROWS + 63) / 64, 9);
    k_qkv<<<gq, 256, 0, stream>>>(comb, Bt, b2, C);

    k_att<<<(N_NODES + 3) / 4, 256, 0, stream>>>(C, accum);
    k_final<<<1, 256, 0, stream>>>(ow, opb, ob, accum, out);
}

// Round 5
// 928.790 us; speedup vs baseline: 12.7809x; 1.2434x over previous
//
#include <hip/hip_runtime.h>
#include <hip/hip_bf16.h>
#include <math.h>

#define N_NODES 50000
#define N_EDGES 1600000
#define M_ROWS  100000   // 2 tokens per node

// ---------------- workspace layout (bytes) ----------------
// Lifetimes: h, csr die after k_agg; C (written by k_qkv) overlaps them.
// xb dies after k_hg.
static const size_t H_OFF    = 0;                 // h bf16 [50000][512] = 51,200,000
static const size_t CSR_OFF  = 51200000;          // int [E] = 6,400,000 -> 57,600,000
static const size_t C_OFF    = 0;                 // C bf16 [100000][520] = 104,000,000 (after h/csr dead)
static const size_t COMB_OFF = 104000000;         // bf16 [100000][256] = 51,200,000 -> 155,200,000
static const size_t ROW_OFF  = 155200000;         // int [N+1]
static const size_t CNT_OFF  = 155400064;         // int [N]
static const size_t CUR_OFF  = 155600128;         // int [N]
static const size_t DIS_OFF  = 155800192;         // f32 [N]
static const size_t DINV_OFF = 156000256;         // f32 [N]
static const size_t BT_OFF   = 156200320;         // bf16 [576][256] = 294,912
static const size_t B2_OFF   = 156495232;         // f32 [576]
static const size_t WP_OFF   = 156497536;         // f32 [256]
static const size_t U_OFF    = 156498560;         // f32 [8][256]
static const size_t CH_OFF   = 156506752;         // f32 [8]
static const size_t FLAG_OFF = 156506816;         // int
static const size_t ACC_OFF  = 156506880;         // double
static const size_t XB_OFF   = 156506944;         // xb bf16 [50000][320] = 32,000,000
static const size_t WT2_OFF  = 188506944;         // bf16 [512][320] = 327,680
static const size_t WS_NEED  = 188834624;

typedef __attribute__((ext_vector_type(8))) short short8v;
typedef __attribute__((ext_vector_type(4))) float f32x4;

__device__ __forceinline__ float bf_lo(unsigned int u) { return __uint_as_float(u << 16); }
__device__ __forceinline__ float bf_hi(unsigned int u) { return __uint_as_float(u & 0xffff0000u); }
__device__ __forceinline__ unsigned short f2bf(float f) {
    unsigned int x = __float_as_uint(f);
    return (unsigned short)((x + 0x7fffu + ((x >> 16) & 1u)) >> 16);   // RNE
}

// ---------------- kernels ----------------

__global__ void k_guard(float* out) { if (threadIdx.x == 0) out[0] = -12345.0f; }

// probe raw edge buffer: int64 layout has all odd int32 words == 0 (ids < 2^31)
__global__ void k_detect(const int* __restrict__ raw, int* __restrict__ flag) {
    if (raw[2 * threadIdx.x + 1] != 0) atomicOr(flag, 1);
}

__device__ __forceinline__ void load_edge(const int* raw, int is32, int e, int& s, int& d) {
    if (is32) { s = raw[e]; d = raw[N_EDGES + e]; }
    else      { s = raw[2 * (size_t)e]; d = raw[2 * ((size_t)N_EDGES + e)]; }
}

__global__ __launch_bounds__(256) void k_deg(const int* __restrict__ raw,
                                             const int* __restrict__ flag,
                                             int* __restrict__ cnt) {
    int e = blockIdx.x * 256 + threadIdx.x;
    if (e >= N_EDGES) return;
    int s, d; load_edge(raw, *flag, e, s, d);
    atomicAdd(&cnt[d], 1);
}

__global__ __launch_bounds__(256) void k_norm(const int* __restrict__ cnt,
                                              float* __restrict__ dis, float* __restrict__ dinv) {
    int n = blockIdx.x * 256 + threadIdx.x;
    if (n < N_NODES) {
        float d = 1.0f + (float)cnt[n];
        float r = rsqrtf(d);
        dis[n]  = r;
        dinv[n] = r * r;
    }
}

// exclusive scan of cnt[50000] -> rowptr[50001], single block of 1024
__global__ __launch_bounds__(1024) void k_scan(const int* __restrict__ cnt,
                                               int* __restrict__ rowptr) {
    __shared__ int part[1024];
    const int CH = 49;
    int tid = threadIdx.x;
    int base = tid * CH;
    int s = 0;
    for (int i = 0; i < CH; ++i) {
        int idx = base + i;
        if (idx < N_NODES) s += cnt[idx];
    }
    part[tid] = s;
    __syncthreads();
    for (int off = 1; off < 1024; off <<= 1) {
        int v = (tid >= off) ? part[tid - off] : 0;
        __syncthreads();
        part[tid] += v;
        __syncthreads();
    }
    int excl = (tid == 0) ? 0 : part[tid - 1];
    for (int i = 0; i < CH; ++i) {
        int idx = base + i;
        if (idx < N_NODES) { rowptr[idx] = excl; excl += cnt[idx]; }
    }
    if (tid == 1023) rowptr[N_NODES] = excl;
}

__global__ __launch_bounds__(256) void k_place(const int* __restrict__ raw,
                                               const int* __restrict__ flag,
                                               const int* __restrict__ rowptr,
                                               int* __restrict__ cur,
                                               int* __restrict__ csr) {
    int e = blockIdx.x * 256 + threadIdx.x;
    if (e >= N_EDGES) return;
    int s, d; load_edge(raw, *flag, e, s, d);
    int pos = rowptr[d] + atomicAdd(&cur[d], 1);
    csr[pos] = s;
}

// x fp32 [N][300] -> xb bf16 [N][320] (zero-padded K tail)
__global__ __launch_bounds__(256) void k_cvtx(const float* __restrict__ x,
                                              unsigned short* __restrict__ xb) {
    int idx = blockIdx.x * 256 + threadIdx.x;    // one per (row, 4-col group)
    int row = idx / 80, g = idx - row * 80;
    if (row >= N_NODES) return;
    int c0 = g * 4;
    ushort4 o;
    if (c0 < 300) {
        float4 v = *reinterpret_cast<const float4*>(x + (size_t)row * 300 + c0);
        o.x = f2bf(v.x); o.y = f2bf(v.y); o.z = f2bf(v.z); o.w = f2bf(v.w);
    } else {
        o = make_ushort4(0, 0, 0, 0);
    }
    *reinterpret_cast<ushort4*>(xb + (size_t)row * 320 + c0) = o;
}

// Wt2[j][k] = block-diag(Ws, Wf) transposed: j<256 -> Ws[k][j] (k<100);
// j>=256 -> Wf[k-100][j-256] (100<=k<300); else 0
__global__ __launch_bounds__(256) void k_wt2(const float* __restrict__ Ws,
                                             const float* __restrict__ Wf,
                                             unsigned short* __restrict__ Wt2) {
    int j = blockIdx.x;
    for (int k = threadIdx.x; k < 320; k += 256) {
        float v = 0.0f;
        if (j < 256) { if (k < 100) v = Ws[(size_t)k * 256 + j]; }
        else         { if (k >= 100 && k < 300) v = Wf[(size_t)(k - 100) * 256 + (j - 256)]; }
        Wt2[(size_t)j * 320 + k] = f2bf(v);
    }
}

// MFMA GEMM: h[50000][512] = xb[50000][320] @ Wt2^T  (bf16 in/out, f32 acc)
__global__ __launch_bounds__(256) void k_hg(const unsigned short* __restrict__ xb,
                                            const unsigned short* __restrict__ Wt2,
                                            unsigned short* __restrict__ h) {
    __shared__ __align__(16) unsigned short sA[64][40];
    __shared__ __align__(16) unsigned short sB[64][40];
    int tid  = threadIdx.x;
    int lane = tid & 63, wid = tid >> 6;
    int wm = wid >> 1, wn = wid & 1;
    int arow = tid >> 2, aseg = (tid & 3) * 8;
    int cblk = blockIdx.x, rblk = blockIdx.y;     // col-block fast: A panel L2 reuse
    long grow = (long)rblk * 64 + arow;
    bool aval = grow < N_NODES;
    const unsigned short* aptr = xb + grow * 320 + aseg;
    const unsigned short* bptr = Wt2 + ((long)cblk * 64 + arow) * 320 + aseg;

    f32x4 acc00 = {0,0,0,0}, acc01 = {0,0,0,0}, acc10 = {0,0,0,0}, acc11 = {0,0,0,0};
    int fr = lane & 15, fk = (lane >> 4) * 8;

    for (int ks = 0; ks < 10; ++ks) {
        uint4 av = aval ? *reinterpret_cast<const uint4*>(aptr + ks * 32) : make_uint4(0,0,0,0);
        uint4 bv = *reinterpret_cast<const uint4*>(bptr + ks * 32);
        __syncthreads();
        *reinterpret_cast<uint4*>(&sA[arow][aseg]) = av;
        *reinterpret_cast<uint4*>(&sB[arow][aseg]) = bv;
        __syncthreads();
        short8v a0 = *reinterpret_cast<const short8v*>(&sA[wm * 32 + fr][fk]);
        short8v a1 = *reinterpret_cast<const short8v*>(&sA[wm * 32 + 16 + fr][fk]);
        short8v b0 = *reinterpret_cast<const short8v*>(&sB[wn * 32 + fr][fk]);
        short8v b1 = *reinterpret_cast<const short8v*>(&sB[wn * 32 + 16 + fr][fk]);
        acc00 = __builtin_amdgcn_mfma_f32_16x16x32_bf16(a0, b0, acc00, 0, 0, 0);
        acc01 = __builtin_amdgcn_mfma_f32_16x16x32_bf16(a0, b1, acc01, 0, 0, 0);
        acc10 = __builtin_amdgcn_mfma_f32_16x16x32_bf16(a1, b0, acc10, 0, 0, 0);
        acc11 = __builtin_amdgcn_mfma_f32_16x16x32_bf16(a1, b1, acc11, 0, 0, 0);
    }

    int crow = rblk * 64 + wm * 32;
    int ccol = cblk * 64 + wn * 32;
    int rb = (lane >> 4) * 4;
    #pragma unroll
    for (int mn = 0; mn < 4; ++mn) {
        int m = mn >> 1, nn = mn & 1;
        f32x4 a = (mn == 0) ? acc00 : (mn == 1) ? acc01 : (mn == 2) ? acc10 : acc11;
        int col = ccol + nn * 16 + (lane & 15);
        #pragma unroll
        for (int j = 0; j < 4; ++j) {
            int row = crow + m * 16 + rb + j;
            if (row < N_NODES) h[(size_t)row * 512 + col] = f2bf(a[j]);
        }
    }
}

// one wave per dst node: comb rows 2n (ch 0..255) / 2n+1 (ch 256..511), bf16
__global__ __launch_bounds__(256) void k_agg(const int* __restrict__ csr,
                                             const int* __restrict__ rowptr,
                                             const float* __restrict__ dis,
                                             const float* __restrict__ dinv,
                                             const unsigned short* __restrict__ h,
                                             const float* __restrict__ bs,
                                             const float* __restrict__ bf,
                                             unsigned short* __restrict__ comb) {
    int n    = blockIdx.x * 4 + (threadIdx.x >> 6);
    int lane = threadIdx.x & 63;
    if (n >= N_NODES) return;
    int beg = rowptr[n], end = rowptr[n + 1];
    float a0=0,a1=0,a2=0,a3=0,a4=0,a5=0,a6=0,a7=0;
    for (int e = beg; e < end; ++e) {
        int s = csr[e];
        float c = dis[s];
        uint4 v = *reinterpret_cast<const uint4*>(h + (size_t)s * 512 + lane * 8);
        a0 += c * bf_lo(v.x); a1 += c * bf_hi(v.x);
        a2 += c * bf_lo(v.y); a3 += c * bf_hi(v.y);
        a4 += c * bf_lo(v.z); a5 += c * bf_hi(v.z);
        a6 += c * bf_lo(v.w); a7 += c * bf_hi(v.w);
    }
    float dn = dis[n], di = dinv[n];
    uint4 hv = *reinterpret_cast<const uint4*>(h + (size_t)n * 512 + lane * 8);
    int j0 = lane * 8;
    const float* bp = (lane < 32) ? (bs + j0) : (bf + (j0 - 256));
    float r0 = fmaxf(dn*a0 + di*bf_lo(hv.x) + bp[0], 0.0f);
    float r1 = fmaxf(dn*a1 + di*bf_hi(hv.x) + bp[1], 0.0f);
    float r2 = fmaxf(dn*a2 + di*bf_lo(hv.y) + bp[2], 0.0f);
    float r3 = fmaxf(dn*a3 + di*bf_hi(hv.y) + bp[3], 0.0f);
    float r4 = fmaxf(dn*a4 + di*bf_lo(hv.z) + bp[4], 0.0f);
    float r5 = fmaxf(dn*a5 + di*bf_hi(hv.z) + bp[5], 0.0f);
    float r6 = fmaxf(dn*a6 + di*bf_lo(hv.w) + bp[6], 0.0f);
    float r7 = fmaxf(dn*a7 + di*bf_hi(hv.w) + bp[7], 0.0f);
    uint4 o;
    o.x = (unsigned int)f2bf(r0) | ((unsigned int)f2bf(r1) << 16);
    o.y = (unsigned int)f2bf(r2) | ((unsigned int)f2bf(r3) << 16);
    o.z = (unsigned int)f2bf(r4) | ((unsigned int)f2bf(r5) << 16);
    o.w = (unsigned int)f2bf(r6) | ((unsigned int)f2bf(r7) << 16);
    int row = 2 * n + (lane >> 5);
    int colb = (lane * 8) & 255;
    *reinterpret_cast<uint4*>(comb + (size_t)row * 256 + colb) = o;
}

// w'[i] = sum_j out_w[j] * out_proj_w[j][i]
__global__ __launch_bounds__(256) void k_wprime(const float* __restrict__ ow,
                                                const float* __restrict__ opw,
                                                float* __restrict__ wp) {
    int i = threadIdx.x;
    float s = 0.0f;
    for (int j = 0; j < 256; ++j) s += ow[j] * opw[j * 256 + i];
    wp[i] = s;
}

// u[h][i] = sum_d ipw[512+h*32+d][i] * w'[h*32+d] ;  c[h] = sum_d ipb[...]*w'[...]
__global__ __launch_bounds__(256) void k_u(const float* __restrict__ ipw,
                                           const float* __restrict__ ipb,
                                           const float* __restrict__ wp,
                                           float* __restrict__ u, float* __restrict__ ch) {
    int hd = blockIdx.x, i = threadIdx.x;
    float s = 0.0f;
    for (int d = 0; d < 32; ++d)
        s += ipw[(size_t)(512 + hd * 32 + d) * 256 + i] * wp[hd * 32 + d];
    u[hd * 256 + i] = s;
    if (i == 0) {
        float c = 0.0f;
        for (int d = 0; d < 32; ++d) c += ipb[512 + hd * 32 + d] * wp[hd * 32 + d];
        ch[hd] = c;
    }
}

// Bt[j][k] bf16: j<512 -> ipw[j][k]; 512..519 -> u[j-512][k]; else 0.
__global__ __launch_bounds__(256) void k_makeB(const float* __restrict__ ipw,
                                               const float* __restrict__ ipb,
                                               const float* __restrict__ u,
                                               const float* __restrict__ ch,
                                               unsigned short* __restrict__ Bt,
                                               float* __restrict__ b2) {
    int j = blockIdx.x, k = threadIdx.x;
    float v = 0.0f;
    if (j < 512)      v = ipw[(size_t)j * 256 + k];
    else if (j < 520) v = u[(j - 512) * 256 + k];
    Bt[(size_t)j * 256 + k] = f2bf(v);
    if (k == 0) b2[j] = (j < 512) ? ipb[j] : ((j < 520) ? ch[j - 512] : 0.0f);
}

// MFMA GEMM: C[100000][520] = comb[M][256] @ Bt^T + b2, bf16 out
__global__ __launch_bounds__(256) void k_qkv(const unsigned short* __restrict__ comb,
                                             const unsigned short* __restrict__ Bt,
                                             const float* __restrict__ b2,
                                             unsigned short* __restrict__ C) {
    __shared__ __align__(16) unsigned short sA[64][40];
    __shared__ __align__(16) unsigned short sB[64][40];
    int tid  = threadIdx.x;
    int lane = tid & 63, wid = tid >> 6;
    int wm = wid >> 1, wn = wid & 1;
    int arow = tid >> 2, aseg = (tid & 3) * 8;
    int cblk = blockIdx.x, rblk = blockIdx.y;     // col-block fast: A panel L2 reuse
    long grow = (long)rblk * 64 + arow;
    bool aval = grow < M_ROWS;
    const unsigned short* aptr = comb + grow * 256 + aseg;
    const unsigned short* bptr = Bt + ((long)cblk * 64 + arow) * 256 + aseg;

    f32x4 acc00 = {0,0,0,0}, acc01 = {0,0,0,0}, acc10 = {0,0,0,0}, acc11 = {0,0,0,0};
    int fr = lane & 15, fk = (lane >> 4) * 8;

    for (int ks = 0; ks < 8; ++ks) {
        uint4 av = aval ? *reinterpret_cast<const uint4*>(aptr + ks * 32) : make_uint4(0,0,0,0);
        uint4 bv = *reinterpret_cast<const uint4*>(bptr + ks * 32);
        __syncthreads();
        *reinterpret_cast<uint4*>(&sA[arow][aseg]) = av;
        *reinterpret_cast<uint4*>(&sB[arow][aseg]) = bv;
        __syncthreads();
        short8v a0 = *reinterpret_cast<const short8v*>(&sA[wm * 32 + fr][fk]);
        short8v a1 = *reinterpret_cast<const short8v*>(&sA[wm * 32 + 16 + fr][fk]);
        short8v b0 = *reinterpret_cast<const short8v*>(&sB[wn * 32 + fr][fk]);
        short8v b1 = *reinterpret_cast<const short8v*>(&sB[wn * 32 + 16 + fr][fk]);
        acc00 = __builtin_amdgcn_mfma_f32_16x16x32_bf16(a0, b0, acc00, 0, 0, 0);
        acc01 = __builtin_amdgcn_mfma_f32_16x16x32_bf16(a0, b1, acc01, 0, 0, 0);
        acc10 = __builtin_amdgcn_mfma_f32_16x16x32_bf16(a1, b0, acc10, 0, 0, 0);
        acc11 = __builtin_amdgcn_mfma_f32_16x16x32_bf16(a1, b1, acc11, 0, 0, 0);
    }

    int crow = rblk * 64 + wm * 32;
    int ccol = cblk * 64 + wn * 32;
    int rb = (lane >> 4) * 4;
    #pragma unroll
    for (int mn = 0; mn < 4; ++mn) {
        int m = mn >> 1, nn = mn & 1;
        f32x4 a = (mn == 0) ? acc00 : (mn == 1) ? acc01 : (mn == 2) ? acc10 : acc11;
        int col = ccol + nn * 16 + (lane & 15);
        if (col < 520) {
            float bias = b2[col];
            #pragma unroll
            for (int j = 0; j < 4; ++j) {
                int row = crow + m * 16 + rb + j;
                if (row < M_ROWS) C[(size_t)row * 520 + col] = f2bf(a[j] + bias);
            }
        }
    }
}

// finalize: wave per node; scores+softmax+vw combine; block -> f64 atomic
__global__ __launch_bounds__(256) void k_att(const unsigned short* __restrict__ C,
                                             double* __restrict__ accum) {
    __shared__ float sQK[4][2][536];   // padded: elem e stored at e + (e>>5)
    __shared__ float red[4];
    int tid = threadIdx.x;
    int lane = tid & 63, wid = tid >> 6;
    int n = blockIdx.x * 4 + wid;

    if (n < N_NODES) {
        for (int c = lane; c < 130; c += 64) {
            int r = (c >= 65), co = c - r * 65;
            int off = co * 8;
            uint4 v = *reinterpret_cast<const uint4*>(C + ((size_t)(2 * n + r) * 520 + off));
            float f0 = bf_lo(v.x), f1 = bf_hi(v.x), f2 = bf_lo(v.y), f3 = bf_hi(v.y);
            float f4 = bf_lo(v.z), f5 = bf_hi(v.z), f6 = bf_lo(v.w), f7 = bf_hi(v.w);
            float* dst = &sQK[wid][r][0];
            dst[(off+0) + ((off+0)>>5)] = f0; dst[(off+1) + ((off+1)>>5)] = f1;
            dst[(off+2) + ((off+2)>>5)] = f2; dst[(off+3) + ((off+3)>>5)] = f3;
            dst[(off+4) + ((off+4)>>5)] = f4; dst[(off+5) + ((off+5)>>5)] = f5;
            dst[(off+6) + ((off+6)>>5)] = f6; dst[(off+7) + ((off+7)>>5)] = f7;
        }
    }
    __syncthreads();

    float acc = 0.0f;
    if (lane < 32 && n < N_NODES) {
        int hd = lane >> 2, t = (lane >> 1) & 1, t2 = lane & 1;
        const float* Q  = &sQK[wid][t][0];
        const float* K2 = &sQK[wid][t2][0];
        int qb = 33 * hd;
        int kb = 264 + 33 * hd;
        float s = 0.0f;
        #pragma unroll 8
        for (int d = 0; d < 32; ++d) s += Q[qb + d] * K2[kb + d];
        s *= 0.17677669529663687f; // 1/sqrt(32)
        float so = __shfl_xor(s, 1);
        float m  = fmaxf(s, so);
        float e  = expf(s - m), eo = expf(so - m);
        float w  = e / (e + eo);
        acc = w * K2[528 + hd];
    }
    #pragma unroll
    for (int off = 1; off < 32; off <<= 1) acc += __shfl_xor(acc, off);
    if (lane == 0) red[wid] = acc;
    __syncthreads();
    if (tid == 0) atomicAdd(accum, (double)(red[0] + red[1] + red[2] + red[3]));
}

__global__ __launch_bounds__(256) void k_final(const float* __restrict__ ow,
                                               const float* __restrict__ opb,
                                               const float* __restrict__ ob,
                                               const double* __restrict__ accum,
                                               float* __restrict__ out) {
    __shared__ float red[256];
    int tid = threadIdx.x;
    red[tid] = ow[tid] * opb[tid];
    __syncthreads();
    for (int s = 128; s > 0; s >>= 1) {
        if (tid < s) red[tid] += red[tid + s];
        __syncthreads();
    }
    if (tid == 0)
        out[0] = (float)(accum[0] / (2.0 * N_NODES) + (double)red[0] + (double)ob[0]);
}

// ---------------- launch ----------------
extern "C" void kernel_launch(void* const* d_in, const int* in_sizes, int n_in,
                              void* d_out, int out_size, void* d_ws, size_t ws_size,
                              hipStream_t stream) {
    const float* x   = (const float*)d_in[0];
    const int*   ei  = (const int*)d_in[1];
    const float* Ws  = (const float*)d_in[2];
    const float* bs  = (const float*)d_in[3];
    const float* Wf  = (const float*)d_in[4];
    const float* bf  = (const float*)d_in[5];
    const float* ipw = (const float*)d_in[6];
    const float* ipb = (const float*)d_in[7];
    const float* opw = (const float*)d_in[8];
    const float* opb = (const float*)d_in[9];
    const float* ow  = (const float*)d_in[10];
    const float* ob  = (const float*)d_in[11];
    float* out = (float*)d_out;

    if (ws_size < WS_NEED) { k_guard<<<1, 64, 0, stream>>>(out); return; }

    char* ws = (char*)d_ws;
    unsigned short* h    = (unsigned short*)(ws + H_OFF);
    int*            csr  = (int*)           (ws + CSR_OFF);
    unsigned short* C    = (unsigned short*)(ws + C_OFF);
    unsigned short* comb = (unsigned short*)(ws + COMB_OFF);
    int*            row  = (int*)           (ws + ROW_OFF);
    int*            cnt  = (int*)           (ws + CNT_OFF);
    int*            cur  = (int*)           (ws + CUR_OFF);
    float*          dis  = (float*)         (ws + DIS_OFF);
    float*          dinv = (float*)         (ws + DINV_OFF);
    unsigned short* Bt   = (unsigned short*)(ws + BT_OFF);
    float*          b2   = (float*)         (ws + B2_OFF);
    float*          wp   = (float*)         (ws + WP_OFF);
    float*          u    = (float*)         (ws + U_OFF);
    float*          chv  = (float*)         (ws + CH_OFF);
    int*            flag = (int*)           (ws + FLAG_OFF);
    double*         accum= (double*)        (ws + ACC_OFF);
    unsigned short* xb   = (unsigned short*)(ws + XB_OFF);
    unsigned short* Wt2  = (unsigned short*)(ws + WT2_OFF);

    hipMemsetAsync(cnt,   0, (size_t)N_NODES * 4, stream);
    hipMemsetAsync(cur,   0, (size_t)N_NODES * 4, stream);
    hipMemsetAsync(flag,  0, 4, stream);
    hipMemsetAsync(accum, 0, 8, stream);

    k_detect<<<1, 256, 0, stream>>>(ei, flag);
    k_deg   <<<(N_EDGES + 255) / 256, 256, 0, stream>>>(ei, flag, cnt);
    k_norm  <<<(N_NODES + 255) / 256, 256, 0, stream>>>(cnt, dis, dinv);
    k_scan  <<<1, 1024, 0, stream>>>(cnt, row);
    k_place <<<(N_EDGES + 255) / 256, 256, 0, stream>>>(ei, flag, row, cur, csr);

    k_cvtx<<<(N_NODES * 80 + 255) / 256, 256, 0, stream>>>(x, xb);
    k_wt2 <<<512, 256, 0, stream>>>(Ws, Wf, Wt2);
    dim3 gh(8, (N_NODES + 63) / 64);
    k_hg  <<<gh, 256, 0, stream>>>(xb, Wt2, h);

    k_agg<<<(N_NODES + 3) / 4, 256, 0, stream>>>(csr, row, dis, dinv, h, bs, bf, comb);

    k_wprime<<<1,   256, 0, stream>>>(ow, opw, wp);
    k_u     <<<8,   256, 0, stream>>>(ipw, ipb, wp, u, chv);
    k_makeB <<<576, 256, 0, stream>>>(ipw, ipb, u, chv, Bt, b2);

    dim3 gq(9, (M_ROWS + 63) / 64);
    k_qkv<<<gq, 256, 0, stream>>>(comb, Bt, b2, C);

    k_att<<<(N_NODES + 3) / 4, 256, 0, stream>>>(C, accum);
    k_final<<<1, 256, 0, stream>>>(ow, opb, ob, accum, out);
}

// Round 6
// 874.441 us; speedup vs baseline: 13.5753x; 1.0622x over previous
//
#include <hip/hip_runtime.h>
#include <hip/hip_bf16.h>
#include <math.h>

#define N_NODES 50000
#define N_EDGES 1600000
#define M_ROWS  100000   // 2 tokens per node

// ---------------- workspace layout (bytes) ----------------
// Lifetimes: xb, y, csr die after k_comb; C (written by k_qkv) overlaps them.
static const size_t XB_OFF   = 0;                 // xb bf16 [50000][320] = 32,000,000
static const size_t Y_OFF    = 32000000;          // y  bf16 [50000][320] = 32,000,000 -> 64,000,000
static const size_t CSR_OFF  = 64000000;          // int [E] = 6,400,000 -> 70,400,000
static const size_t C_OFF    = 0;                 // C bf16 [100000][520] = 104,000,000 (after xb/y/csr dead)
static const size_t COMB_OFF = 104000000;         // bf16 [100000][256] = 51,200,000 -> 155,200,000
static const size_t ROW_OFF  = 155200000;         // int [N+1]
static const size_t CNT_OFF  = 155400064;         // int [N]
static const size_t CUR_OFF  = 155600128;         // int [N]
static const size_t DIS_OFF  = 155800192;         // f32 [N]
static const size_t DINV_OFF = 156000256;         // f32 [N]
static const size_t BT_OFF   = 156200320;         // bf16 [576][256] = 294,912
static const size_t B2_OFF   = 156495232;         // f32 [576]
static const size_t WP_OFF   = 156497536;         // f32 [256]
static const size_t U_OFF    = 156498560;         // f32 [8][256]
static const size_t CH_OFF   = 156506752;         // f32 [8]
static const size_t FLAG_OFF = 156506816;         // int
static const size_t ACC_OFF  = 156506880;         // double
static const size_t WT2_OFF  = 156506944;         // bf16 [512][320] = 327,680
static const size_t WS_NEED  = 156834624;

typedef __attribute__((ext_vector_type(8))) short short8v;
typedef __attribute__((ext_vector_type(4))) float f32x4;

__device__ __forceinline__ float bf_lo(unsigned int u) { return __uint_as_float(u << 16); }
__device__ __forceinline__ float bf_hi(unsigned int u) { return __uint_as_float(u & 0xffff0000u); }
__device__ __forceinline__ unsigned short f2bf(float f) {
    unsigned int x = __float_as_uint(f);
    return (unsigned short)((x + 0x7fffu + ((x >> 16) & 1u)) >> 16);   // RNE
}

// ---------------- kernels ----------------

__global__ void k_guard(float* out) { if (threadIdx.x == 0) out[0] = -12345.0f; }

// probe raw edge buffer: int64 layout has all odd int32 words == 0 (ids < 2^31)
__global__ void k_detect(const int* __restrict__ raw, int* __restrict__ flag) {
    if (raw[2 * threadIdx.x + 1] != 0) atomicOr(flag, 1);
}

__device__ __forceinline__ void load_edge(const int* raw, int is32, int e, int& s, int& d) {
    if (is32) { s = raw[e]; d = raw[N_EDGES + e]; }
    else      { s = raw[2 * (size_t)e]; d = raw[2 * ((size_t)N_EDGES + e)]; }
}

__global__ __launch_bounds__(256) void k_deg(const int* __restrict__ raw,
                                             const int* __restrict__ flag,
                                             int* __restrict__ cnt) {
    int e = blockIdx.x * 256 + threadIdx.x;
    if (e >= N_EDGES) return;
    int s, d; load_edge(raw, *flag, e, s, d);
    atomicAdd(&cnt[d], 1);
}

__global__ __launch_bounds__(256) void k_norm(const int* __restrict__ cnt,
                                              float* __restrict__ dis, float* __restrict__ dinv) {
    int n = blockIdx.x * 256 + threadIdx.x;
    if (n < N_NODES) {
        float d = 1.0f + (float)cnt[n];
        float r = rsqrtf(d);
        dis[n]  = r;
        dinv[n] = r * r;
    }
}

// exclusive scan of cnt[50000] -> rowptr[50001], single block of 1024
__global__ __launch_bounds__(1024) void k_scan(const int* __restrict__ cnt,
                                               int* __restrict__ rowptr) {
    __shared__ int part[1024];
    const int CH = 49;
    int tid = threadIdx.x;
    int base = tid * CH;
    int s = 0;
    for (int i = 0; i < CH; ++i) {
        int idx = base + i;
        if (idx < N_NODES) s += cnt[idx];
    }
    part[tid] = s;
    __syncthreads();
    for (int off = 1; off < 1024; off <<= 1) {
        int v = (tid >= off) ? part[tid - off] : 0;
        __syncthreads();
        part[tid] += v;
        __syncthreads();
    }
    int excl = (tid == 0) ? 0 : part[tid - 1];
    for (int i = 0; i < CH; ++i) {
        int idx = base + i;
        if (idx < N_NODES) { rowptr[idx] = excl; excl += cnt[idx]; }
    }
    if (tid == 1023) rowptr[N_NODES] = excl;
}

__global__ __launch_bounds__(256) void k_place(const int* __restrict__ raw,
                                               const int* __restrict__ flag,
                                               const int* __restrict__ rowptr,
                                               int* __restrict__ cur,
                                               int* __restrict__ csr) {
    int e = blockIdx.x * 256 + threadIdx.x;
    if (e >= N_EDGES) return;
    int s, d; load_edge(raw, *flag, e, s, d);
    int pos = rowptr[d] + atomicAdd(&cur[d], 1);
    csr[pos] = s;
}

// x fp32 [N][300] -> xb bf16 [N][320] (zero-padded K tail)
__global__ __launch_bounds__(256) void k_cvtx(const float* __restrict__ x,
                                              unsigned short* __restrict__ xb) {
    int idx = blockIdx.x * 256 + threadIdx.x;    // one per (row, 4-col group)
    int row = idx / 80, g = idx - row * 80;
    if (row >= N_NODES) return;
    int c0 = g * 4;
    ushort4 o;
    if (c0 < 300) {
        float4 v = *reinterpret_cast<const float4*>(x + (size_t)row * 300 + c0);
        o.x = f2bf(v.x); o.y = f2bf(v.y); o.z = f2bf(v.z); o.w = f2bf(v.w);
    } else {
        o = make_ushort4(0, 0, 0, 0);
    }
    *reinterpret_cast<ushort4*>(xb + (size_t)row * 320 + c0) = o;
}

// Wt2[j][k] = block-diag(Ws, Wf) transposed: j<256 -> Ws[k][j] (k<100);
// j>=256 -> Wf[k-100][j-256] (100<=k<300); else 0
__global__ __launch_bounds__(256) void k_wt2(const float* __restrict__ Ws,
                                             const float* __restrict__ Wf,
                                             unsigned short* __restrict__ Wt2) {
    int j = blockIdx.x;
    for (int k = threadIdx.x; k < 320; k += 256) {
        float v = 0.0f;
        if (j < 256) { if (k < 100) v = Ws[(size_t)k * 256 + j]; }
        else         { if (k >= 100 && k < 300) v = Wf[(size_t)(k - 100) * 256 + (j - 256)]; }
        Wt2[(size_t)j * 320 + k] = f2bf(v);
    }
}

// one wave per dst node, x-space aggregation:
// y[n] = dis[n] * sum_e dis[src]*xb[src] + dinv[n]*xb[n]   (320 ch, 40 active lanes)
__global__ __launch_bounds__(256) void k_aggx(const int* __restrict__ csr,
                                              const int* __restrict__ rowptr,
                                              const float* __restrict__ dis,
                                              const float* __restrict__ dinv,
                                              const unsigned short* __restrict__ xb,
                                              unsigned short* __restrict__ y) {
    int n    = blockIdx.x * 4 + (threadIdx.x >> 6);
    int lane = threadIdx.x & 63;
    if (n >= N_NODES || lane >= 40) return;
    int beg = rowptr[n], end = rowptr[n + 1];
    float a0=0,a1=0,a2=0,a3=0,a4=0,a5=0,a6=0,a7=0;
    for (int e = beg; e < end; ++e) {
        int s = csr[e];
        float c = dis[s];
        uint4 v = *reinterpret_cast<const uint4*>(xb + (size_t)s * 320 + lane * 8);
        a0 += c * bf_lo(v.x); a1 += c * bf_hi(v.x);
        a2 += c * bf_lo(v.y); a3 += c * bf_hi(v.y);
        a4 += c * bf_lo(v.z); a5 += c * bf_hi(v.z);
        a6 += c * bf_lo(v.w); a7 += c * bf_hi(v.w);
    }
    float dn = dis[n], di = dinv[n];
    uint4 hv = *reinterpret_cast<const uint4*>(xb + (size_t)n * 320 + lane * 8);
    float r0 = dn*a0 + di*bf_lo(hv.x);
    float r1 = dn*a1 + di*bf_hi(hv.x);
    float r2 = dn*a2 + di*bf_lo(hv.y);
    float r3 = dn*a3 + di*bf_hi(hv.y);
    float r4 = dn*a4 + di*bf_lo(hv.z);
    float r5 = dn*a5 + di*bf_hi(hv.z);
    float r6 = dn*a6 + di*bf_lo(hv.w);
    float r7 = dn*a7 + di*bf_hi(hv.w);
    uint4 o;
    o.x = (unsigned int)f2bf(r0) | ((unsigned int)f2bf(r1) << 16);
    o.y = (unsigned int)f2bf(r2) | ((unsigned int)f2bf(r3) << 16);
    o.z = (unsigned int)f2bf(r4) | ((unsigned int)f2bf(r5) << 16);
    o.w = (unsigned int)f2bf(r6) | ((unsigned int)f2bf(r7) << 16);
    *reinterpret_cast<uint4*>(y + (size_t)n * 320 + lane * 8) = o;
}

// MFMA GEMM + fused bias/ReLU: comb = relu(y @ Wt2^T + bias), token-major layout
__global__ __launch_bounds__(256) void k_comb(const unsigned short* __restrict__ y,
                                              const unsigned short* __restrict__ Wt2,
                                              const float* __restrict__ bs,
                                              const float* __restrict__ bf,
                                              unsigned short* __restrict__ comb) {
    __shared__ __align__(16) unsigned short sA[64][40];
    __shared__ __align__(16) unsigned short sB[64][40];
    int tid  = threadIdx.x;
    int lane = tid & 63, wid = tid >> 6;
    int wm = wid >> 1, wn = wid & 1;
    int arow = tid >> 2, aseg = (tid & 3) * 8;
    int cblk = blockIdx.x, rblk = blockIdx.y;     // col-block fast: A panel L2 reuse
    long grow = (long)rblk * 64 + arow;
    bool aval = grow < N_NODES;
    const unsigned short* aptr = y + grow * 320 + aseg;
    const unsigned short* bptr = Wt2 + ((long)cblk * 64 + arow) * 320 + aseg;

    f32x4 acc00 = {0,0,0,0}, acc01 = {0,0,0,0}, acc10 = {0,0,0,0}, acc11 = {0,0,0,0};
    int fr = lane & 15, fk = (lane >> 4) * 8;

    for (int ks = 0; ks < 10; ++ks) {
        uint4 av = aval ? *reinterpret_cast<const uint4*>(aptr + ks * 32) : make_uint4(0,0,0,0);
        uint4 bv = *reinterpret_cast<const uint4*>(bptr + ks * 32);
        __syncthreads();
        *reinterpret_cast<uint4*>(&sA[arow][aseg]) = av;
        *reinterpret_cast<uint4*>(&sB[arow][aseg]) = bv;
        __syncthreads();
        short8v a0 = *reinterpret_cast<const short8v*>(&sA[wm * 32 + fr][fk]);
        short8v a1 = *reinterpret_cast<const short8v*>(&sA[wm * 32 + 16 + fr][fk]);
        short8v b0 = *reinterpret_cast<const short8v*>(&sB[wn * 32 + fr][fk]);
        short8v b1 = *reinterpret_cast<const short8v*>(&sB[wn * 32 + 16 + fr][fk]);
        acc00 = __builtin_amdgcn_mfma_f32_16x16x32_bf16(a0, b0, acc00, 0, 0, 0);
        acc01 = __builtin_amdgcn_mfma_f32_16x16x32_bf16(a0, b1, acc01, 0, 0, 0);
        acc10 = __builtin_amdgcn_mfma_f32_16x16x32_bf16(a1, b0, acc10, 0, 0, 0);
        acc11 = __builtin_amdgcn_mfma_f32_16x16x32_bf16(a1, b1, acc11, 0, 0, 0);
    }

    int crow = rblk * 64 + wm * 32;
    int ccol = cblk * 64 + wn * 32;
    int rb = (lane >> 4) * 4;
    #pragma unroll
    for (int mn = 0; mn < 4; ++mn) {
        int m = mn >> 1, nn = mn & 1;
        f32x4 a = (mn == 0) ? acc00 : (mn == 1) ? acc01 : (mn == 2) ? acc10 : acc11;
        int col = ccol + nn * 16 + (lane & 15);
        int t  = col >> 8;          // token: 0 (s) / 1 (f)
        int c2 = col & 255;
        float bias = t ? bf[c2] : bs[c2];
        #pragma unroll
        for (int j = 0; j < 4; ++j) {
            int row = crow + m * 16 + rb + j;
            if (row < N_NODES)
                comb[(size_t)(2 * row + t) * 256 + c2] = f2bf(fmaxf(a[j] + bias, 0.0f));
        }
    }
}

// w'[i] = sum_j out_w[j] * out_proj_w[j][i]
__global__ __launch_bounds__(256) void k_wprime(const float* __restrict__ ow,
                                                const float* __restrict__ opw,
                                                float* __restrict__ wp) {
    int i = threadIdx.x;
    float s = 0.0f;
    for (int j = 0; j < 256; ++j) s += ow[j] * opw[j * 256 + i];
    wp[i] = s;
}

// u[h][i] = sum_d ipw[512+h*32+d][i] * w'[h*32+d] ;  c[h] = sum_d ipb[...]*w'[...]
__global__ __launch_bounds__(256) void k_u(const float* __restrict__ ipw,
                                           const float* __restrict__ ipb,
                                           const float* __restrict__ wp,
                                           float* __restrict__ u, float* __restrict__ ch) {
    int hd = blockIdx.x, i = threadIdx.x;
    float s = 0.0f;
    for (int d = 0; d < 32; ++d)
        s += ipw[(size_t)(512 + hd * 32 + d) * 256 + i] * wp[hd * 32 + d];
    u[hd * 256 + i] = s;
    if (i == 0) {
        float c = 0.0f;
        for (int d = 0; d < 32; ++d) c += ipb[512 + hd * 32 + d] * wp[hd * 32 + d];
        ch[hd] = c;
    }
}

// Bt[j][k] bf16: j<512 -> ipw[j][k]; 512..519 -> u[j-512][k]; else 0.
__global__ __launch_bounds__(256) void k_makeB(const float* __restrict__ ipw,
                                               const float* __restrict__ ipb,
                                               const float* __restrict__ u,
                                               const float* __restrict__ ch,
                                               unsigned short* __restrict__ Bt,
                                               float* __restrict__ b2) {
    int j = blockIdx.x, k = threadIdx.x;
    float v = 0.0f;
    if (j < 512)      v = ipw[(size_t)j * 256 + k];
    else if (j < 520) v = u[(j - 512) * 256 + k];
    Bt[(size_t)j * 256 + k] = f2bf(v);
    if (k == 0) b2[j] = (j < 512) ? ipb[j] : ((j < 520) ? ch[j - 512] : 0.0f);
}

// MFMA GEMM: C[100000][520] = comb[M][256] @ Bt^T + b2, bf16 out
__global__ __launch_bounds__(256) void k_qkv(const unsigned short* __restrict__ comb,
                                             const unsigned short* __restrict__ Bt,
                                             const float* __restrict__ b2,
                                             unsigned short* __restrict__ C) {
    __shared__ __align__(16) unsigned short sA[64][40];
    __shared__ __align__(16) unsigned short sB[64][40];
    int tid  = threadIdx.x;
    int lane = tid & 63, wid = tid >> 6;
    int wm = wid >> 1, wn = wid & 1;
    int arow = tid >> 2, aseg = (tid & 3) * 8;
    int cblk = blockIdx.x, rblk = blockIdx.y;     // col-block fast: A panel L2 reuse
    long grow = (long)rblk * 64 + arow;
    bool aval = grow < M_ROWS;
    const unsigned short* aptr = comb + grow * 256 + aseg;
    const unsigned short* bptr = Bt + ((long)cblk * 64 + arow) * 256 + aseg;

    f32x4 acc00 = {0,0,0,0}, acc01 = {0,0,0,0}, acc10 = {0,0,0,0}, acc11 = {0,0,0,0};
    int fr = lane & 15, fk = (lane >> 4) * 8;

    for (int ks = 0; ks < 8; ++ks) {
        uint4 av = aval ? *reinterpret_cast<const uint4*>(aptr + ks * 32) : make_uint4(0,0,0,0);
        uint4 bv = *reinterpret_cast<const uint4*>(bptr + ks * 32);
        __syncthreads();
        *reinterpret_cast<uint4*>(&sA[arow][aseg]) = av;
        *reinterpret_cast<uint4*>(&sB[arow][aseg]) = bv;
        __syncthreads();
        short8v a0 = *reinterpret_cast<const short8v*>(&sA[wm * 32 + fr][fk]);
        short8v a1 = *reinterpret_cast<const short8v*>(&sA[wm * 32 + 16 + fr][fk]);
        short8v b0 = *reinterpret_cast<const short8v*>(&sB[wn * 32 + fr][fk]);
        short8v b1 = *reinterpret_cast<const short8v*>(&sB[wn * 32 + 16 + fr][fk]);
        acc00 = __builtin_amdgcn_mfma_f32_16x16x32_bf16(a0, b0, acc00, 0, 0, 0);
        acc01 = __builtin_amdgcn_mfma_f32_16x16x32_bf16(a0, b1, acc01, 0, 0, 0);
        acc10 = __builtin_amdgcn_mfma_f32_16x16x32_bf16(a1, b0, acc10, 0, 0, 0);
        acc11 = __builtin_amdgcn_mfma_f32_16x16x32_bf16(a1, b1, acc11, 0, 0, 0);
    }

    int crow = rblk * 64 + wm * 32;
    int ccol = cblk * 64 + wn * 32;
    int rb = (lane >> 4) * 4;
    #pragma unroll
    for (int mn = 0; mn < 4; ++mn) {
        int m = mn >> 1, nn = mn & 1;
        f32x4 a = (mn == 0) ? acc00 : (mn == 1) ? acc01 : (mn == 2) ? acc10 : acc11;
        int col = ccol + nn * 16 + (lane & 15);
        if (col < 520) {
            float bias = b2[col];
            #pragma unroll
            for (int j = 0; j < 4; ++j) {
                int row = crow + m * 16 + rb + j;
                if (row < M_ROWS) C[(size_t)row * 520 + col] = f2bf(a[j] + bias);
            }
        }
    }
}

// finalize: wave per node; scores+softmax+vw combine; block -> f64 atomic
__global__ __launch_bounds__(256) void k_att(const unsigned short* __restrict__ C,
                                             double* __restrict__ accum) {
    __shared__ float sQK[4][2][536];   // padded: elem e stored at e + (e>>5)
    __shared__ float red[4];
    int tid = threadIdx.x;
    int lane = tid & 63, wid = tid >> 6;
    int n = blockIdx.x * 4 + wid;

    if (n < N_NODES) {
        for (int c = lane; c < 130; c += 64) {
            int r = (c >= 65), co = c - r * 65;
            int off = co * 8;
            uint4 v = *reinterpret_cast<const uint4*>(C + ((size_t)(2 * n + r) * 520 + off));
            float f0 = bf_lo(v.x), f1 = bf_hi(v.x), f2 = bf_lo(v.y), f3 = bf_hi(v.y);
            float f4 = bf_lo(v.z), f5 = bf_hi(v.z), f6 = bf_lo(v.w), f7 = bf_hi(v.w);
            float* dst = &sQK[wid][r][0];
            dst[(off+0) + ((off+0)>>5)] = f0; dst[(off+1) + ((off+1)>>5)] = f1;
            dst[(off+2) + ((off+2)>>5)] = f2; dst[(off+3) + ((off+3)>>5)] = f3;
            dst[(off+4) + ((off+4)>>5)] = f4; dst[(off+5) + ((off+5)>>5)] = f5;
            dst[(off+6) + ((off+6)>>5)] = f6; dst[(off+7) + ((off+7)>>5)] = f7;
        }
    }
    __syncthreads();

    float acc = 0.0f;
    if (lane < 32 && n < N_NODES) {
        int hd = lane >> 2, t = (lane >> 1) & 1, t2 = lane & 1;
        const float* Q  = &sQK[wid][t][0];
        const float* K2 = &sQK[wid][t2][0];
        int qb = 33 * hd;
        int kb = 264 + 33 * hd;
        float s = 0.0f;
        #pragma unroll 8
        for (int d = 0; d < 32; ++d) s += Q[qb + d] * K2[kb + d];
        s *= 0.17677669529663687f; // 1/sqrt(32)
        float so = __shfl_xor(s, 1);
        float m  = fmaxf(s, so);
        float e  = expf(s - m), eo = expf(so - m);
        float w  = e / (e + eo);
        acc = w * K2[528 + hd];
    }
    #pragma unroll
    for (int off = 1; off < 32; off <<= 1) acc += __shfl_xor(acc, off);
    if (lane == 0) red[wid] = acc;
    __syncthreads();
    if (tid == 0) atomicAdd(accum, (double)(red[0] + red[1] + red[2] + red[3]));
}

__global__ __launch_bounds__(256) void k_final(const float* __restrict__ ow,
                                               const float* __restrict__ opb,
                                               const float* __restrict__ ob,
                                               const double* __restrict__ accum,
                                               float* __restrict__ out) {
    __shared__ float red[256];
    int tid = threadIdx.x;
    red[tid] = ow[tid] * opb[tid];
    __syncthreads();
    for (int s = 128; s > 0; s >>= 1) {
        if (tid < s) red[tid] += red[tid + s];
        __syncthreads();
    }
    if (tid == 0)
        out[0] = (float)(accum[0] / (2.0 * N_NODES) + (double)red[0] + (double)ob[0]);
}

// ---------------- launch ----------------
extern "C" void kernel_launch(void* const* d_in, const int* in_sizes, int n_in,
                              void* d_out, int out_size, void* d_ws, size_t ws_size,
                              hipStream_t stream) {
    const float* x   = (const float*)d_in[0];
    const int*   ei  = (const int*)d_in[1];
    const float* Ws  = (const float*)d_in[2];
    const float* bs  = (const float*)d_in[3];
    const float* Wf  = (const float*)d_in[4];
    const float* bf  = (const float*)d_in[5];
    const float* ipw = (const float*)d_in[6];
    const float* ipb = (const float*)d_in[7];
    const float* opw = (const float*)d_in[8];
    const float* opb = (const float*)d_in[9];
    const float* ow  = (const float*)d_in[10];
    const float* ob  = (const float*)d_in[11];
    float* out = (float*)d_out;

    if (ws_size < WS_NEED) { k_guard<<<1, 64, 0, stream>>>(out); return; }

    char* ws = (char*)d_ws;
    unsigned short* xb   = (unsigned short*)(ws + XB_OFF);
    unsigned short* y    = (unsigned short*)(ws + Y_OFF);
    int*            csr  = (int*)           (ws + CSR_OFF);
    unsigned short* C    = (unsigned short*)(ws + C_OFF);
    unsigned short* comb = (unsigned short*)(ws + COMB_OFF);
    int*            row  = (int*)           (ws + ROW_OFF);
    int*            cnt  = (int*)           (ws + CNT_OFF);
    int*            cur  = (int*)           (ws + CUR_OFF);
    float*          dis  = (float*)         (ws + DIS_OFF);
    float*          dinv = (float*)         (ws + DINV_OFF);
    unsigned short* Bt   = (unsigned short*)(ws + BT_OFF);
    float*          b2   = (float*)         (ws + B2_OFF);
    float*          wp   = (float*)         (ws + WP_OFF);
    float*          u    = (float*)         (ws + U_OFF);
    float*          chv  = (float*)         (ws + CH_OFF);
    int*            flag = (int*)           (ws + FLAG_OFF);
    double*         accum= (double*)        (ws + ACC_OFF);
    unsigned short* Wt2  = (unsigned short*)(ws + WT2_OFF);

    hipMemsetAsync(cnt,   0, (size_t)N_NODES * 4, stream);
    hipMemsetAsync(cur,   0, (size_t)N_NODES * 4, stream);
    hipMemsetAsync(flag,  0, 4, stream);
    hipMemsetAsync(accum, 0, 8, stream);

    k_detect<<<1, 256, 0, stream>>>(ei, flag);
    k_deg   <<<(N_EDGES + 255) / 256, 256, 0, stream>>>(ei, flag, cnt);
    k_norm  <<<(N_NODES + 255) / 256, 256, 0, stream>>>(cnt, dis, dinv);
    k_scan  <<<1, 1024, 0, stream>>>(cnt, row);
    k_place <<<(N_EDGES + 255) / 256, 256, 0, stream>>>(ei, flag, row, cur, csr);

    k_cvtx<<<(N_NODES * 80 + 255) / 256, 256, 0, stream>>>(x, xb);
    k_wt2 <<<512, 256, 0, stream>>>(Ws, Wf, Wt2);

    k_aggx<<<(N_NODES + 3) / 4, 256, 0, stream>>>(csr, row, dis, dinv, xb, y);

    k_wprime<<<1,   256, 0, stream>>>(ow, opw, wp);
    k_u     <<<8,   256, 0, stream>>>(ipw, ipb, wp, u, chv);
    k_makeB <<<576, 256, 0, stream>>>(ipw, ipb, u, chv, Bt, b2);

    dim3 gc(8, (N_NODES + 63) / 64);
    k_comb<<<gc, 256, 0, stream>>>(y, Wt2, bs, bf, comb);

    dim3 gq(9, (M_ROWS + 63) / 64);
    k_qkv<<<gq, 256, 0, stream>>>(comb, Bt, b2, C);

    k_att<<<(N_NODES + 3) / 4, 256, 0, stream>>>(C, accum);
    k_final<<<1, 256, 0, stream>>>(ow, opb, ob, accum, out);
}

// Round 7
// 714.584 us; speedup vs baseline: 16.6122x; 1.2237x over previous
//
#include <hip/hip_runtime.h>
#include <hip/hip_bf16.h>
#include <math.h>

#define N_NODES 50000
#define N_EDGES 1600000
#define M_ROWS  100000   // 2 tokens per node

// ---------------- workspace layout (bytes) ----------------
// Lifetimes: xb, y, csr die after k_comb.
static const size_t XB_OFF   = 0;                 // xb bf16 [50000][320] = 32,000,000
static const size_t Y_OFF    = 32000000;          // y  bf16 [50000][320] = 32,000,000 -> 64,000,000
static const size_t CSR_OFF  = 64000000;          // int [E] = 6,400,000 -> 70,400,000
static const size_t COMB_OFF = 104000000;         // bf16 [100000][256] = 51,200,000 -> 155,200,000
static const size_t ROW_OFF  = 155200000;         // int [N+1]
static const size_t CNT_OFF  = 155400064;         // int [N]
static const size_t CUR_OFF  = 155600128;         // int [N]
static const size_t DIS_OFF  = 155800192;         // f32 [N]
static const size_t DINV_OFF = 156000256;         // f32 [N]
static const size_t BT_OFF   = 156200320;         // bf16 [576][256] = 294,912
static const size_t B2_OFF   = 156495232;         // f32 [576]
static const size_t WP_OFF   = 156497536;         // f32 [256]
static const size_t U_OFF    = 156498560;         // f32 [8][256]
static const size_t CH_OFF   = 156506752;         // f32 [8]
static const size_t FLAG_OFF = 156506816;         // int
static const size_t ACC_OFF  = 156506880;         // double
static const size_t WT2_OFF  = 156506944;         // bf16 [512][320] = 327,680
static const size_t WS_NEED  = 156834624;

typedef __attribute__((ext_vector_type(8))) short short8v;
typedef __attribute__((ext_vector_type(4))) float f32x4;

__device__ __forceinline__ float bf_lo(unsigned int u) { return __uint_as_float(u << 16); }
__device__ __forceinline__ float bf_hi(unsigned int u) { return __uint_as_float(u & 0xffff0000u); }
__device__ __forceinline__ float bf2f(unsigned short u) { return __uint_as_float((unsigned int)u << 16); }
__device__ __forceinline__ unsigned short f2bf(float f) {
    unsigned int x = __float_as_uint(f);
    return (unsigned short)((x + 0x7fffu + ((x >> 16) & 1u)) >> 16);   // RNE
}

// ---------------- kernels ----------------

__global__ void k_guard(float* out) { if (threadIdx.x == 0) out[0] = -12345.0f; }

// probe raw edge buffer: int64 layout has all odd int32 words == 0 (ids < 2^31)
__global__ void k_detect(const int* __restrict__ raw, int* __restrict__ flag) {
    if (raw[2 * threadIdx.x + 1] != 0) atomicOr(flag, 1);
}

__device__ __forceinline__ void load_edge(const int* raw, int is32, int e, int& s, int& d) {
    if (is32) { s = raw[e]; d = raw[N_EDGES + e]; }
    else      { s = raw[2 * (size_t)e]; d = raw[2 * ((size_t)N_EDGES + e)]; }
}

__global__ __launch_bounds__(256) void k_deg(const int* __restrict__ raw,
                                             const int* __restrict__ flag,
                                             int* __restrict__ cnt) {
    int e = blockIdx.x * 256 + threadIdx.x;
    if (e >= N_EDGES) return;
    int s, d; load_edge(raw, *flag, e, s, d);
    atomicAdd(&cnt[d], 1);
}

__global__ __launch_bounds__(256) void k_norm(const int* __restrict__ cnt,
                                              float* __restrict__ dis, float* __restrict__ dinv) {
    int n = blockIdx.x * 256 + threadIdx.x;
    if (n < N_NODES) {
        float d = 1.0f + (float)cnt[n];
        float r = rsqrtf(d);
        dis[n]  = r;
        dinv[n] = r * r;
    }
}

// exclusive scan of cnt[50000] -> rowptr[50001], single block of 1024
__global__ __launch_bounds__(1024) void k_scan(const int* __restrict__ cnt,
                                               int* __restrict__ rowptr) {
    __shared__ int part[1024];
    const int CH = 49;
    int tid = threadIdx.x;
    int base = tid * CH;
    int s = 0;
    for (int i = 0; i < CH; ++i) {
        int idx = base + i;
        if (idx < N_NODES) s += cnt[idx];
    }
    part[tid] = s;
    __syncthreads();
    for (int off = 1; off < 1024; off <<= 1) {
        int v = (tid >= off) ? part[tid - off] : 0;
        __syncthreads();
        part[tid] += v;
        __syncthreads();
    }
    int excl = (tid == 0) ? 0 : part[tid - 1];
    for (int i = 0; i < CH; ++i) {
        int idx = base + i;
        if (idx < N_NODES) { rowptr[idx] = excl; excl += cnt[idx]; }
    }
    if (tid == 1023) rowptr[N_NODES] = excl;
}

__global__ __launch_bounds__(256) void k_place(const int* __restrict__ raw,
                                               const int* __restrict__ flag,
                                               const int* __restrict__ rowptr,
                                               int* __restrict__ cur,
                                               int* __restrict__ csr) {
    int e = blockIdx.x * 256 + threadIdx.x;
    if (e >= N_EDGES) return;
    int s, d; load_edge(raw, *flag, e, s, d);
    int pos = rowptr[d] + atomicAdd(&cur[d], 1);
    csr[pos] = s;
}

// x fp32 [N][300] -> xb bf16 [N][320] (zero-padded K tail)
__global__ __launch_bounds__(256) void k_cvtx(const float* __restrict__ x,
                                              unsigned short* __restrict__ xb) {
    int idx = blockIdx.x * 256 + threadIdx.x;    // one per (row, 4-col group)
    int row = idx / 80, g = idx - row * 80;
    if (row >= N_NODES) return;
    int c0 = g * 4;
    ushort4 o;
    if (c0 < 300) {
        float4 v = *reinterpret_cast<const float4*>(x + (size_t)row * 300 + c0);
        o.x = f2bf(v.x); o.y = f2bf(v.y); o.z = f2bf(v.z); o.w = f2bf(v.w);
    } else {
        o = make_ushort4(0, 0, 0, 0);
    }
    *reinterpret_cast<ushort4*>(xb + (size_t)row * 320 + c0) = o;
}

// Wt2[j][k] = block-diag(Ws, Wf) transposed
__global__ __launch_bounds__(256) void k_wt2(const float* __restrict__ Ws,
                                             const float* __restrict__ Wf,
                                             unsigned short* __restrict__ Wt2) {
    int j = blockIdx.x;
    for (int k = threadIdx.x; k < 320; k += 256) {
        float v = 0.0f;
        if (j < 256) { if (k < 100) v = Ws[(size_t)k * 256 + j]; }
        else         { if (k >= 100 && k < 300) v = Wf[(size_t)(k - 100) * 256 + (j - 256)]; }
        Wt2[(size_t)j * 320 + k] = f2bf(v);
    }
}

// one wave per dst node, x-space aggregation, 4-edge unrolled for MLP:
// y[n] = dis[n] * sum_e dis[src]*xb[src] + dinv[n]*xb[n]   (320 ch, 40 active lanes)
__global__ __launch_bounds__(256) void k_aggx(const int* __restrict__ csr,
                                              const int* __restrict__ rowptr,
                                              const float* __restrict__ dis,
                                              const float* __restrict__ dinv,
                                              const unsigned short* __restrict__ xb,
                                              unsigned short* __restrict__ y) {
    int n    = blockIdx.x * 4 + (threadIdx.x >> 6);
    int lane = threadIdx.x & 63;
    if (n >= N_NODES || lane >= 40) return;
    int beg = rowptr[n], end = rowptr[n + 1];
    float a0=0,a1=0,a2=0,a3=0,a4=0,a5=0,a6=0,a7=0;
    int e = beg;
    for (; e + 4 <= end; e += 4) {
        int s0 = csr[e], s1 = csr[e+1], s2 = csr[e+2], s3 = csr[e+3];
        float c0 = dis[s0], c1 = dis[s1], c2 = dis[s2], c3 = dis[s3];
        uint4 v0 = *reinterpret_cast<const uint4*>(xb + (size_t)s0 * 320 + lane * 8);
        uint4 v1 = *reinterpret_cast<const uint4*>(xb + (size_t)s1 * 320 + lane * 8);
        uint4 v2 = *reinterpret_cast<const uint4*>(xb + (size_t)s2 * 320 + lane * 8);
        uint4 v3 = *reinterpret_cast<const uint4*>(xb + (size_t)s3 * 320 + lane * 8);
        a0 += c0*bf_lo(v0.x); a1 += c0*bf_hi(v0.x); a2 += c0*bf_lo(v0.y); a3 += c0*bf_hi(v0.y);
        a4 += c0*bf_lo(v0.z); a5 += c0*bf_hi(v0.z); a6 += c0*bf_lo(v0.w); a7 += c0*bf_hi(v0.w);
        a0 += c1*bf_lo(v1.x); a1 += c1*bf_hi(v1.x); a2 += c1*bf_lo(v1.y); a3 += c1*bf_hi(v1.y);
        a4 += c1*bf_lo(v1.z); a5 += c1*bf_hi(v1.z); a6 += c1*bf_lo(v1.w); a7 += c1*bf_hi(v1.w);
        a0 += c2*bf_lo(v2.x); a1 += c2*bf_hi(v2.x); a2 += c2*bf_lo(v2.y); a3 += c2*bf_hi(v2.y);
        a4 += c2*bf_lo(v2.z); a5 += c2*bf_hi(v2.z); a6 += c2*bf_lo(v2.w); a7 += c2*bf_hi(v2.w);
        a0 += c3*bf_lo(v3.x); a1 += c3*bf_hi(v3.x); a2 += c3*bf_lo(v3.y); a3 += c3*bf_hi(v3.y);
        a4 += c3*bf_lo(v3.z); a5 += c3*bf_hi(v3.z); a6 += c3*bf_lo(v3.w); a7 += c3*bf_hi(v3.w);
    }
    for (; e < end; ++e) {
        int s = csr[e];
        float c = dis[s];
        uint4 v = *reinterpret_cast<const uint4*>(xb + (size_t)s * 320 + lane * 8);
        a0 += c*bf_lo(v.x); a1 += c*bf_hi(v.x); a2 += c*bf_lo(v.y); a3 += c*bf_hi(v.y);
        a4 += c*bf_lo(v.z); a5 += c*bf_hi(v.z); a6 += c*bf_lo(v.w); a7 += c*bf_hi(v.w);
    }
    float dn = dis[n], di = dinv[n];
    uint4 hv = *reinterpret_cast<const uint4*>(xb + (size_t)n * 320 + lane * 8);
    float r0 = dn*a0 + di*bf_lo(hv.x);
    float r1 = dn*a1 + di*bf_hi(hv.x);
    float r2 = dn*a2 + di*bf_lo(hv.y);
    float r3 = dn*a3 + di*bf_hi(hv.y);
    float r4 = dn*a4 + di*bf_lo(hv.z);
    float r5 = dn*a5 + di*bf_hi(hv.z);
    float r6 = dn*a6 + di*bf_lo(hv.w);
    float r7 = dn*a7 + di*bf_hi(hv.w);
    uint4 o;
    o.x = (unsigned int)f2bf(r0) | ((unsigned int)f2bf(r1) << 16);
    o.y = (unsigned int)f2bf(r2) | ((unsigned int)f2bf(r3) << 16);
    o.z = (unsigned int)f2bf(r4) | ((unsigned int)f2bf(r5) << 16);
    o.w = (unsigned int)f2bf(r6) | ((unsigned int)f2bf(r7) << 16);
    *reinterpret_cast<uint4*>(y + (size_t)n * 320 + lane * 8) = o;
}

// MFMA GEMM + fused bias/ReLU: comb = relu(y @ Wt2^T + bias), token-major layout
__global__ __launch_bounds__(256) void k_comb(const unsigned short* __restrict__ y,
                                              const unsigned short* __restrict__ Wt2,
                                              const float* __restrict__ bs,
                                              const float* __restrict__ bf,
                                              unsigned short* __restrict__ comb) {
    __shared__ __align__(16) unsigned short sA[64][40];
    __shared__ __align__(16) unsigned short sB[64][40];
    int tid  = threadIdx.x;
    int lane = tid & 63, wid = tid >> 6;
    int wm = wid >> 1, wn = wid & 1;
    int arow = tid >> 2, aseg = (tid & 3) * 8;
    int cblk = blockIdx.x, rblk = blockIdx.y;
    long grow = (long)rblk * 64 + arow;
    bool aval = grow < N_NODES;
    const unsigned short* aptr = y + grow * 320 + aseg;
    const unsigned short* bptr = Wt2 + ((long)cblk * 64 + arow) * 320 + aseg;

    f32x4 acc00 = {0,0,0,0}, acc01 = {0,0,0,0}, acc10 = {0,0,0,0}, acc11 = {0,0,0,0};
    int fr = lane & 15, fk = (lane >> 4) * 8;

    for (int ks = 0; ks < 10; ++ks) {
        uint4 av = aval ? *reinterpret_cast<const uint4*>(aptr + ks * 32) : make_uint4(0,0,0,0);
        uint4 bv = *reinterpret_cast<const uint4*>(bptr + ks * 32);
        __syncthreads();
        *reinterpret_cast<uint4*>(&sA[arow][aseg]) = av;
        *reinterpret_cast<uint4*>(&sB[arow][aseg]) = bv;
        __syncthreads();
        short8v a0 = *reinterpret_cast<const short8v*>(&sA[wm * 32 + fr][fk]);
        short8v a1 = *reinterpret_cast<const short8v*>(&sA[wm * 32 + 16 + fr][fk]);
        short8v b0 = *reinterpret_cast<const short8v*>(&sB[wn * 32 + fr][fk]);
        short8v b1 = *reinterpret_cast<const short8v*>(&sB[wn * 32 + 16 + fr][fk]);
        acc00 = __builtin_amdgcn_mfma_f32_16x16x32_bf16(a0, b0, acc00, 0, 0, 0);
        acc01 = __builtin_amdgcn_mfma_f32_16x16x32_bf16(a0, b1, acc01, 0, 0, 0);
        acc10 = __builtin_amdgcn_mfma_f32_16x16x32_bf16(a1, b0, acc10, 0, 0, 0);
        acc11 = __builtin_amdgcn_mfma_f32_16x16x32_bf16(a1, b1, acc11, 0, 0, 0);
    }

    int crow = rblk * 64 + wm * 32;
    int ccol = cblk * 64 + wn * 32;
    int rb = (lane >> 4) * 4;
    #pragma unroll
    for (int mn = 0; mn < 4; ++mn) {
        int m = mn >> 1, nn = mn & 1;
        f32x4 a = (mn == 0) ? acc00 : (mn == 1) ? acc01 : (mn == 2) ? acc10 : acc11;
        int col = ccol + nn * 16 + (lane & 15);
        int t  = col >> 8;          // token: 0 (s) / 1 (f)
        int c2 = col & 255;
        float bias = t ? bf[c2] : bs[c2];
        #pragma unroll
        for (int j = 0; j < 4; ++j) {
            int row = crow + m * 16 + rb + j;
            if (row < N_NODES)
                comb[(size_t)(2 * row + t) * 256 + c2] = f2bf(fmaxf(a[j] + bias, 0.0f));
        }
    }
}

// w'[i] = sum_j out_w[j] * out_proj_w[j][i]
__global__ __launch_bounds__(256) void k_wprime(const float* __restrict__ ow,
                                                const float* __restrict__ opw,
                                                float* __restrict__ wp) {
    int i = threadIdx.x;
    float s = 0.0f;
    for (int j = 0; j < 256; ++j) s += ow[j] * opw[j * 256 + i];
    wp[i] = s;
}

// u[h][i] = sum_d ipw[512+h*32+d][i] * w'[h*32+d] ;  c[h] = sum_d ipb[...]*w'[...]
__global__ __launch_bounds__(256) void k_u(const float* __restrict__ ipw,
                                           const float* __restrict__ ipb,
                                           const float* __restrict__ wp,
                                           float* __restrict__ u, float* __restrict__ ch) {
    int hd = blockIdx.x, i = threadIdx.x;
    float s = 0.0f;
    for (int d = 0; d < 32; ++d)
        s += ipw[(size_t)(512 + hd * 32 + d) * 256 + i] * wp[hd * 32 + d];
    u[hd * 256 + i] = s;
    if (i == 0) {
        float c = 0.0f;
        for (int d = 0; d < 32; ++d) c += ipb[512 + hd * 32 + d] * wp[hd * 32 + d];
        ch[hd] = c;
    }
}

// Bt[j][k] bf16: j<512 -> ipw[j][k]; 512..519 -> u[j-512][k]; else 0.
__global__ __launch_bounds__(256) void k_makeB(const float* __restrict__ ipw,
                                               const float* __restrict__ ipb,
                                               const float* __restrict__ u,
                                               const float* __restrict__ ch,
                                               unsigned short* __restrict__ Bt,
                                               float* __restrict__ b2) {
    int j = blockIdx.x, k = threadIdx.x;
    float v = 0.0f;
    if (j < 512)      v = ipw[(size_t)j * 256 + k];
    else if (j < 520) v = u[(j - 512) * 256 + k];
    Bt[(size_t)j * 256 + k] = f2bf(v);
    if (k == 0) b2[j] = (j < 512) ? ipb[j] : ((j < 520) ? ch[j - 512] : 0.0f);
}

// Fused QKV-GEMM + attention finalize. Block = 64 token rows (32 nodes).
// Phase A: 9 col-blocks of 64x64 MFMA tile -> C-tile bf16 in LDS (padded cols).
// Phase B: per (node,head,t) softmax over t2, vw combine, block reduce -> f64 atomic.
__global__ __launch_bounds__(256) void k_fuse(const unsigned short* __restrict__ comb,
                                              const unsigned short* __restrict__ Bt,
                                              const float* __restrict__ b2,
                                              double* __restrict__ accum) {
    __shared__ __align__(16) unsigned short CT[64][544];  // padded col c -> c + (c>>5)
    __shared__ __align__(16) unsigned short sA[64][40];
    __shared__ __align__(16) unsigned short sB[64][40];
    __shared__ float red[256];

    int tid  = threadIdx.x;
    int lane = tid & 63, wid = tid >> 6;
    int wm = wid >> 1, wn = wid & 1;
    int arow = tid >> 2, aseg = (tid & 3) * 8;
    long grow = (long)blockIdx.x * 64 + arow;
    bool aval = grow < M_ROWS;
    const unsigned short* aptr = comb + grow * 256 + aseg;
    int fr = lane & 15, fk = (lane >> 4) * 8;
    int rb = (lane >> 4) * 4;

    for (int cb = 0; cb < 9; ++cb) {
        const unsigned short* bptr = Bt + ((long)cb * 64 + arow) * 256 + aseg;
        f32x4 acc00 = {0,0,0,0}, acc01 = {0,0,0,0}, acc10 = {0,0,0,0}, acc11 = {0,0,0,0};
        for (int ks = 0; ks < 8; ++ks) {
            uint4 av = aval ? *reinterpret_cast<const uint4*>(aptr + ks * 32) : make_uint4(0,0,0,0);
            uint4 bv = *reinterpret_cast<const uint4*>(bptr + ks * 32);
            __syncthreads();
            *reinterpret_cast<uint4*>(&sA[arow][aseg]) = av;
            *reinterpret_cast<uint4*>(&sB[arow][aseg]) = bv;
            __syncthreads();
            short8v a0 = *reinterpret_cast<const short8v*>(&sA[wm * 32 + fr][fk]);
            short8v a1 = *reinterpret_cast<const short8v*>(&sA[wm * 32 + 16 + fr][fk]);
            short8v b0 = *reinterpret_cast<const short8v*>(&sB[wn * 32 + fr][fk]);
            short8v b1 = *reinterpret_cast<const short8v*>(&sB[wn * 32 + 16 + fr][fk]);
            acc00 = __builtin_amdgcn_mfma_f32_16x16x32_bf16(a0, b0, acc00, 0, 0, 0);
            acc01 = __builtin_amdgcn_mfma_f32_16x16x32_bf16(a0, b1, acc01, 0, 0, 0);
            acc10 = __builtin_amdgcn_mfma_f32_16x16x32_bf16(a1, b0, acc10, 0, 0, 0);
            acc11 = __builtin_amdgcn_mfma_f32_16x16x32_bf16(a1, b1, acc11, 0, 0, 0);
        }
        int ccol = cb * 64 + wn * 32;
        #pragma unroll
        for (int mn = 0; mn < 4; ++mn) {
            int m = mn >> 1, nn = mn & 1;
            f32x4 a = (mn == 0) ? acc00 : (mn == 1) ? acc01 : (mn == 2) ? acc10 : acc11;
            int col = ccol + nn * 16 + (lane & 15);
            if (col < 520) {
                float bias = b2[col];
                int pcol = col + (col >> 5);
                #pragma unroll
                for (int j = 0; j < 4; ++j)
                    CT[wm * 32 + m * 16 + rb + j][pcol] = f2bf(a[j] + bias);
            }
        }
    }
    __syncthreads();

    // Phase B: 512 items = 32 nodes x 8 heads x 2 query-tokens; 2 items/thread
    float acc = 0.0f;
    #pragma unroll
    for (int ii = 0; ii < 2; ++ii) {
        int it = tid + ii * 256;
        int node32 = it >> 4;
        int rem = it & 15, hd = rem >> 1, t = rem & 1;
        int gnode = blockIdx.x * 32 + node32;
        if (gnode < N_NODES) {
            const unsigned short* qr = &CT[2 * node32 + t][0];
            const unsigned short* k0 = &CT[2 * node32 + 0][0];
            const unsigned short* k1 = &CT[2 * node32 + 1][0];
            int qb = hd * 32 + hd;             // pad(hd*32)
            int kb = 256 + hd * 32 + 8 + hd;   // pad(256+hd*32)
            float s0 = 0.0f, s1 = 0.0f;
            #pragma unroll 8
            for (int d = 0; d < 32; ++d) {
                float qv = bf2f(qr[qb + d]);
                s0 += qv * bf2f(k0[kb + d]);
                s1 += qv * bf2f(k1[kb + d]);
            }
            const float sc = 0.17677669529663687f;  // 1/sqrt(32)
            s0 *= sc; s1 *= sc;
            float m = fmaxf(s0, s1);
            float e0 = expf(s0 - m), e1 = expf(s1 - m);
            float inv = 1.0f / (e0 + e1);
            float vw0 = bf2f(k0[528 + hd]);    // pad(512+hd)
            float vw1 = bf2f(k1[528 + hd]);
            acc += (e0 * vw0 + e1 * vw1) * inv;
        }
    }
    red[tid] = acc;
    __syncthreads();
    for (int s = 128; s > 0; s >>= 1) {
        if (tid < s) red[tid] += red[tid + s];
        __syncthreads();
    }
    if (tid == 0) atomicAdd(accum, (double)red[0]);
}

__global__ __launch_bounds__(256) void k_final(const float* __restrict__ ow,
                                               const float* __restrict__ opb,
                                               const float* __restrict__ ob,
                                               const double* __restrict__ accum,
                                               float* __restrict__ out) {
    __shared__ float red[256];
    int tid = threadIdx.x;
    red[tid] = ow[tid] * opb[tid];
    __syncthreads();
    for (int s = 128; s > 0; s >>= 1) {
        if (tid < s) red[tid] += red[tid + s];
        __syncthreads();
    }
    if (tid == 0)
        out[0] = (float)(accum[0] / (2.0 * N_NODES) + (double)red[0] + (double)ob[0]);
}

// ---------------- launch ----------------
extern "C" void kernel_launch(void* const* d_in, const int* in_sizes, int n_in,
                              void* d_out, int out_size, void* d_ws, size_t ws_size,
                              hipStream_t stream) {
    const float* x   = (const float*)d_in[0];
    const int*   ei  = (const int*)d_in[1];
    const float* Ws  = (const float*)d_in[2];
    const float* bs  = (const float*)d_in[3];
    const float* Wf  = (const float*)d_in[4];
    const float* bf  = (const float*)d_in[5];
    const float* ipw = (const float*)d_in[6];
    const float* ipb = (const float*)d_in[7];
    const float* opw = (const float*)d_in[8];
    const float* opb = (const float*)d_in[9];
    const float* ow  = (const float*)d_in[10];
    const float* ob  = (const float*)d_in[11];
    float* out = (float*)d_out;

    if (ws_size < WS_NEED) { k_guard<<<1, 64, 0, stream>>>(out); return; }

    char* ws = (char*)d_ws;
    unsigned short* xb   = (unsigned short*)(ws + XB_OFF);
    unsigned short* y    = (unsigned short*)(ws + Y_OFF);
    int*            csr  = (int*)           (ws + CSR_OFF);
    unsigned short* comb = (unsigned short*)(ws + COMB_OFF);
    int*            row  = (int*)           (ws + ROW_OFF);
    int*            cnt  = (int*)           (ws + CNT_OFF);
    int*            cur  = (int*)           (ws + CUR_OFF);
    float*          dis  = (float*)         (ws + DIS_OFF);
    float*          dinv = (float*)         (ws + DINV_OFF);
    unsigned short* Bt   = (unsigned short*)(ws + BT_OFF);
    float*          b2   = (float*)         (ws + B2_OFF);
    float*          wp   = (float*)         (ws + WP_OFF);
    float*          u    = (float*)         (ws + U_OFF);
    float*          chv  = (float*)         (ws + CH_OFF);
    int*            flag = (int*)           (ws + FLAG_OFF);
    double*         accum= (double*)        (ws + ACC_OFF);
    unsigned short* Wt2  = (unsigned short*)(ws + WT2_OFF);

    hipMemsetAsync(cnt,   0, (size_t)N_NODES * 4, stream);
    hipMemsetAsync(cur,   0, (size_t)N_NODES * 4, stream);
    hipMemsetAsync(flag,  0, 4, stream);
    hipMemsetAsync(accum, 0, 8, stream);

    k_detect<<<1, 256, 0, stream>>>(ei, flag);
    k_deg   <<<(N_EDGES + 255) / 256, 256, 0, stream>>>(ei, flag, cnt);
    k_norm  <<<(N_NODES + 255) / 256, 256, 0, stream>>>(cnt, dis, dinv);
    k_scan  <<<1, 1024, 0, stream>>>(cnt, row);
    k_place <<<(N_EDGES + 255) / 256, 256, 0, stream>>>(ei, flag, row, cur, csr);

    k_cvtx<<<(N_NODES * 80 + 255) / 256, 256, 0, stream>>>(x, xb);
    k_wt2 <<<512, 256, 0, stream>>>(Ws, Wf, Wt2);

    k_aggx<<<(N_NODES + 3) / 4, 256, 0, stream>>>(csr, row, dis, dinv, xb, y);

    k_wprime<<<1,   256, 0, stream>>>(ow, opw, wp);
    k_u     <<<8,   256, 0, stream>>>(ipw, ipb, wp, u, chv);
    k_makeB <<<576, 256, 0, stream>>>(ipw, ipb, u, chv, Bt, b2);

    dim3 gc(8, (N_NODES + 63) / 64);
    k_comb<<<gc, 256, 0, stream>>>(y, Wt2, bs, bf, comb);

    k_fuse<<<(M_ROWS + 63) / 64, 256, 0, stream>>>(comb, Bt, b2, accum);
    k_final<<<1, 256, 0, stream>>>(ow, opb, ob, accum, out);
}